// Round 5
// baseline (1920.865 us; speedup 1.0000x reference)
//
#include <hip/hip_runtime.h>

#define EPSF     1e-8f
#define LAMBF    0.5f
#define L2NORMF  1e-4f
#define NUSERS   100000
#define NITEMS   50000
#define EMB      64
#define RREL     3
#define NNZ_     1000000
#define IGNNZ    500000
#define BB       512
#define KK       100

#define IGTOT    (RREL * IGNNZ)               // 1.5M
#define TOTE     (IGTOT + NNZ_)               // 2.5M edges total
#define NBIN_SEG 782                          // ceil(50000/64)
#define NBINS    (4 * NBIN_SEG)               // 3128 coarse bins
#define NBLK     128                          // bucketing blocks
#define BTH      1024                         // bucketing block size
#define SLICE    ((TOTE + NBLK - 1) / NBLK)   // 19532

__device__ __forceinline__ int edge_bin(int i, const int* ig_rows, const int* train_cols) {
    if (i < IGTOT) return (i / IGNNZ) * NBIN_SEG + (ig_rows[i] >> 6);
    return 3 * NBIN_SEG + (train_cols[i - IGTOT] >> 6);
}

// user -> batch slot map + batch-item flags
__global__ void scatter_maps(const int* __restrict__ user, const int* __restrict__ item,
                             int* __restrict__ slot, int* __restrict__ iflag) {
    int i = blockIdx.x * blockDim.x + threadIdx.x;
    if (i < BB) slot[user[i]] = i;
    if (i < BB * KK) iflag[item[i]] = 1;
}

// pass 1: per-block LDS histogram over coarse bins -> pcnt[block][bin] (plain writes)
__global__ void pass1_count(const int* __restrict__ ig_rows, const int* __restrict__ train_cols,
                            int* __restrict__ pcnt) {
    __shared__ int h[NBINS];
    int b = blockIdx.x, t = threadIdx.x;
    for (int i = t; i < NBINS; i += BTH) h[i] = 0;
    __syncthreads();
    int s = b * SLICE, e = min(s + SLICE, TOTE);
    for (int i = s + t; i < e; i += BTH)
        atomicAdd(&h[edge_bin(i, ig_rows, train_cols)], 1);
    __syncthreads();
    for (int i = t; i < NBINS; i += BTH) pcnt[b * NBINS + i] = h[i];
}

// tot[bin] = sum over blocks (coalesced)
__global__ void scan_tot(const int* __restrict__ pcnt, int* __restrict__ tot) {
    int bin = blockIdx.x * blockDim.x + threadIdx.x;
    if (bin >= NBINS) return;
    int s = 0;
    for (int b = 0; b < NBLK; b++) s += pcnt[b * NBINS + bin];
    tot[bin] = s;
}

// exclusive scan of tot[NBINS] -> binbase (single block, 1024 threads, 4 bins/thread)
__global__ void scan_bins(const int* __restrict__ tot, int* __restrict__ binbase) {
    __shared__ int csum[1024];
    int t = threadIdx.x;
    int base = t * 4;
    int v0 = (base + 0 < NBINS) ? tot[base + 0] : 0;
    int v1 = (base + 1 < NBINS) ? tot[base + 1] : 0;
    int v2 = (base + 2 < NBINS) ? tot[base + 2] : 0;
    int v3 = (base + 3 < NBINS) ? tot[base + 3] : 0;
    int s = v0 + v1 + v2 + v3;
    csum[t] = s;
    __syncthreads();
    for (int d = 1; d < 1024; d <<= 1) {
        int x = (t >= d) ? csum[t - d] : 0;
        __syncthreads();
        csum[t] += x;
        __syncthreads();
    }
    int run = csum[t] - s;   // exclusive
    if (base + 0 < NBINS) { binbase[base + 0] = run; run += v0; }
    if (base + 1 < NBINS) { binbase[base + 1] = run; run += v1; }
    if (base + 2 < NBINS) { binbase[base + 2] = run; run += v2; }
    if (base + 3 < NBINS) { binbase[base + 3] = run; run += v3; }
    if (t == 0) binbase[NBINS] = TOTE;
}

// per-(block,bin) base offsets (coalesced across bin)
__global__ void scan_obase(const int* __restrict__ pcnt, const int* __restrict__ binbase,
                           int* __restrict__ obase) {
    int bin = blockIdx.x * blockDim.x + threadIdx.x;
    if (bin >= NBINS) return;
    int run = binbase[bin];
    for (int b = 0; b < NBLK; b++) {
        obase[b * NBINS + bin] = run;
        run += pcnt[b * NBINS + bin];
    }
}

// pass 2: place edges; rank via LDS counters seeded with obase (no global atomics)
// payload: bcol = (src<<6)|dest_low ; bval (ig only)
__global__ void pass2_scatter(const int* __restrict__ ig_rows, const int* __restrict__ ig_cols,
                              const float* __restrict__ ig_vals, const int* __restrict__ train_rows,
                              const int* __restrict__ train_cols, const int* __restrict__ obase,
                              int* __restrict__ bcol, float* __restrict__ bval) {
    __shared__ int pos[NBINS];
    int b = blockIdx.x, t = threadIdx.x;
    for (int i = t; i < NBINS; i += BTH) pos[i] = obase[b * NBINS + i];
    __syncthreads();
    int s = b * SLICE, e = min(s + SLICE, TOTE);
    for (int i = s + t; i < e; i += BTH) {
        if (i < IGTOT) {
            int dest = ig_rows[i];
            int bin = (i / IGNNZ) * NBIN_SEG + (dest >> 6);
            int slot = atomicAdd(&pos[bin], 1);
            bcol[slot] = (ig_cols[i] << 6) | (dest & 63);
            bval[slot] = ig_vals[i];
        } else {
            int e2 = i - IGTOT;
            int dest = train_cols[e2];
            int bin = 3 * NBIN_SEG + (dest >> 6);
            int slot = atomicAdd(&pos[bin], 1);
            bcol[slot] = (train_rows[e2] << 6) | (dest & 63);
        }
    }
}

// ig gather: block per 64-dest bin, LDS accumulator, fused /deg @Wp -> prop2
__global__ void ig_gather_lds(const float* __restrict__ item_emb, const int* __restrict__ binbase,
                              const int* __restrict__ bcol, const float* __restrict__ bval,
                              const float* __restrict__ Wp, float* __restrict__ prop2, int seg) {
    __shared__ float acc[64][64];
    __shared__ float deg[64];
    int t = threadIdx.x, w = t >> 6, lane = t & 63;
    int bin = seg * NBIN_SEG + blockIdx.x;
    for (int i = t; i < 64 * 64; i += 256) ((float*)acc)[i] = 0.f;
    if (t < 64) deg[t] = 0.f;
    __syncthreads();
    int s = binbase[bin], e = binbase[bin + 1];
    for (int base = s + w * 64; base < e; base += 4 * 64) {
        int n = min(64, e - base);
        int p = 0; float v = 0.f;
        if (lane < n) { p = bcol[base + lane]; v = bval[base + lane]; }
        if (lane < n) atomicAdd(&deg[p & 63], v);
        for (int j = 0; j < n; j++) {
            int pj = __shfl(p, j);
            float vj = __shfl(v, j);
            int c = pj >> 6, rl = pj & 63;
            atomicAdd(&acc[rl][lane], vj * item_emb[c * 64 + lane]);
        }
    }
    __syncthreads();
    int row0 = blockIdx.x * 64;
    for (int r = w; r < 64; r += 4) {
        int grow = row0 + r;
        if (grow >= NITEMS) break;
        float inv = 1.0f / (deg[r] + EPSF);
        float o = 0.f;
#pragma unroll
        for (int k = 0; k < 64; k++) o += acc[r][k] * Wp[k * 64 + lane];
        prop2[grow * 64 + lane] = o * inv;
    }
}

// train gather: block per 64-dest bin, LDS accumulator, fused @W at flagged rows -> itf2
__global__ void train_gather_lds(const float* __restrict__ user_emb, const int* __restrict__ binbase,
                                 const int* __restrict__ bcol, const int* __restrict__ iflag,
                                 const float* __restrict__ Wm, float* __restrict__ itf2) {
    __shared__ float acc[64][64];
    int t = threadIdx.x, w = t >> 6, lane = t & 63;
    int bin = 3 * NBIN_SEG + blockIdx.x;
    for (int i = t; i < 64 * 64; i += 256) ((float*)acc)[i] = 0.f;
    __syncthreads();
    int s = binbase[bin], e = binbase[bin + 1];
    for (int base = s + w * 64; base < e; base += 4 * 64) {
        int n = min(64, e - base);
        int p = 0;
        if (lane < n) p = bcol[base + lane];
        for (int j = 0; j < n; j++) {
            int pj = __shfl(p, j);
            int u = pj >> 6, rl = pj & 63;
            atomicAdd(&acc[rl][lane], user_emb[u * 64 + lane]);
        }
    }
    __syncthreads();
    int row0 = blockIdx.x * 64;
    for (int r = w; r < 64; r += 4) {
        int grow = row0 + r;
        if (grow >= NITEMS) break;
        if (!iflag[grow]) continue;
        float o = 0.f;
#pragma unroll
        for (int k = 0; k < 64; k++) o += acc[r][k] * Wm[k * 64 + lane];
        itf2[grow * 64 + lane] = o;
    }
}

// filtered relation scan: only edges whose user is in the batch contribute
__global__ void rel_scan(const int* __restrict__ rows, const int* __restrict__ cols,
                         const int* __restrict__ slot, const float* __restrict__ item_emb,
                         const float* __restrict__ item_prop2,
                         float* __restrict__ acc_neigh, float* __restrict__ acc_prop,
                         float* __restrict__ ubc) {
    int lane = threadIdx.x & 63;
    int wave = (blockIdx.x * blockDim.x + threadIdx.x) >> 6;
    int nwaves = (gridDim.x * blockDim.x) >> 6;
    for (int base = wave * 64; base < NNZ_; base += nwaves * 64) {
        int e = base + lane;
        int s = -1, c = 0;
        if (e < NNZ_) {
            s = slot[rows[e]];
            c = cols[e];
        }
        unsigned long long mask = __ballot(s >= 0);
        while (mask) {
            int j = __builtin_ctzll(mask);
            mask &= mask - 1;
            int bs = __shfl(s, j);
            int bc = __shfl(c, j);
            atomicAdd(&acc_neigh[bs * EMB + lane], item_emb[bc * EMB + lane]);
            atomicAdd(&acc_prop[bs * EMB + lane], item_prop2[bc * EMB + lane]);
            if (lane == 0) atomicAdd(&ubc[bs], 1.0f);
        }
    }
}

// per batch row: proj = tmp_user_item_p[user[b]] @ Wb, then
// score2[b,k] += dot(proj, [item_emb[it] | item_prop2[it]])
__global__ void proj_score2(const int* __restrict__ user, const int* __restrict__ slot,
                            const float* __restrict__ ubc, const float* __restrict__ acc_neigh,
                            const float* __restrict__ acc_prop, const float* __restrict__ Wb,
                            const int* __restrict__ item, const float* __restrict__ item_emb,
                            const float* __restrict__ item_prop2, float* __restrict__ score2) {
    int b = blockIdx.x;
    int tid = threadIdx.x;               // 256
    __shared__ float tbuf[128];
    __shared__ float p[128];
    int rep = slot[user[b]];
    float inv = 1.0f / (ubc[rep] + EPSF);
    if (tid < 64)       tbuf[tid] = acc_neigh[rep * 64 + tid] * inv;
    else if (tid < 128) tbuf[tid] = acc_prop[rep * 64 + (tid - 64)] * inv;
    __syncthreads();
    if (tid < 128) {
        float o = 0.f;
#pragma unroll 8
        for (int k = 0; k < 128; k++) o += tbuf[k] * Wb[k * 128 + tid];
        p[tid] = o;
    }
    __syncthreads();
    int wave = tid >> 6, lane = tid & 63;
    for (int k = wave; k < KK; k += 4) {
        int it = item[b * KK + k];
        float s = p[lane] * item_emb[it * 64 + lane] + p[64 + lane] * item_prop2[it * 64 + lane];
        for (int off = 32; off > 0; off >>= 1) s += __shfl_xor(s, off);
        if (lane == 0) score2[b * KK + k] += s;
    }
}

// final: ufeat + @W in-block, then score1 + LAMB*score2/R + l2
__global__ void final_k(const int* __restrict__ user, const int* __restrict__ item,
                        const int* __restrict__ slot, const float* __restrict__ ubc,
                        const float* __restrict__ acc_neigh, const float* __restrict__ mw,
                        const float* __restrict__ W, const float* __restrict__ user_emb,
                        const float* __restrict__ item_emb, const float* __restrict__ itf2,
                        const float* __restrict__ score2, float* __restrict__ out,
                        float* __restrict__ l2out) {
    int b = blockIdx.x;
    int tid = threadIdx.x;               // 256
    int wave = tid >> 6, lane = tid & 63;
    __shared__ float uf[64], u1[64], u2[64];
    __shared__ float red[4];
    int u = user[b];
    if (tid < 64) {
        int rep = slot[u];
        float w0 = mw[0], w1 = mw[1], w2 = mw[2];
        float c0 = ubc[0 * BB + rep], c1 = ubc[1 * BB + rep], c2 = ubc[2 * BB + rep];
        float invT = 1.0f / (c0 * w0 + c1 * w1 + c2 * w2 + EPSF);
        float f = (c0 * w0 * invT) / (c0 + EPSF) * acc_neigh[(0 * BB + rep) * 64 + tid]
                + (c1 * w1 * invT) / (c1 + EPSF) * acc_neigh[(1 * BB + rep) * 64 + tid]
                + (c2 * w2 * invT) / (c2 + EPSF) * acc_neigh[(2 * BB + rep) * 64 + tid];
        uf[tid] = f;
        u1[tid] = user_emb[u * 64 + tid];
    }
    __syncthreads();
    if (tid < 64) {
        float o = 0.f;
#pragma unroll
        for (int k = 0; k < 64; k++) o += uf[k] * W[k * 64 + tid];
        u2[tid] = o;
    }
    __syncthreads();
    float l2part = 0.f;
    for (int k = wave; k < KK; k += 4) {
        int it = item[b * KK + k];
        float e1 = item_emb[it * 64 + lane], e2 = itf2[it * 64 + lane];
        float s = u1[lane] * e1 + u2[lane] * e2;
        float q = e1 * e1 + e2 * e2;
        for (int off = 32; off > 0; off >>= 1) {
            s += __shfl_xor(s, off);
            q += __shfl_xor(q, off);
        }
        if (lane == 0) {
            out[b * KK + k] = s + LAMBF * (score2[b * KK + k] * (1.0f / (float)RREL));
            l2part += q;
        }
    }
    float su = u1[lane] * u1[lane] + u2[lane] * u2[lane];
    for (int off = 32; off > 0; off >>= 1) su += __shfl_xor(su, off);
    if (wave == 0 && lane == 0) l2part += (float)KK * su;
    if (lane == 0) red[wave] = l2part;
    __syncthreads();
    if (tid == 0) atomicAdd(l2out, L2NORMF * (red[0] + red[1] + red[2] + red[3]));
}

extern "C" void kernel_launch(void* const* d_in, const int* in_sizes, int n_in,
                              void* d_out, int out_size, void* d_ws, size_t ws_size,
                              hipStream_t stream) {
    const int*   user       = (const int*)d_in[0];
    const int*   item       = (const int*)d_in[1];
    const int*   rel_rows   = (const int*)d_in[2];
    const int*   rel_cols   = (const int*)d_in[3];
    const int*   ig_rows    = (const int*)d_in[4];
    const int*   ig_cols    = (const int*)d_in[5];
    const float* ig_vals    = (const float*)d_in[6];
    const int*   train_rows = (const int*)d_in[7];
    const int*   train_cols = (const int*)d_in[8];
    const float* user_emb   = (const float*)d_in[9];
    const float* item_emb   = (const float*)d_in[10];
    const float* mw         = (const float*)d_in[11];
    const float* Wb         = (const float*)d_in[12];  // R x 128 x 128
    const float* Wp         = (const float*)d_in[13];  // R x 64 x 64
    const float* W          = (const float*)d_in[14];  // 64 x 64
    float* out = (float*)d_out;

    // ---- workspace layout (4-byte words) ----
    float* ws = (float*)d_ws;
    size_t o = 0;
    int*   user_slot  = (int*)(ws + o); o += NUSERS;          // memset 0xFF
    int*   iflag      = (int*)(ws + o); o += NITEMS;          // memset 0
    int*   pcnt       = (int*)(ws + o); o += (size_t)NBLK * NBINS;
    int*   tot        = (int*)(ws + o); o += NBINS;
    int*   binbase    = (int*)(ws + o); o += NBINS + 1;
    int*   obase      = (int*)(ws + o); o += (size_t)NBLK * NBINS;
    int*   bcol       = (int*)(ws + o); o += TOTE;
    float* bval       = ws + o; o += IGTOT;
    float* item_prop2 = ws + o; o += (size_t)NITEMS * 64;     // reused as itf2 at the end
    // contiguous zero zone:
    float* acc_neigh  = ws + o; o += (size_t)RREL * BB * 64;
    float* acc_prop   = ws + o; o += (size_t)RREL * BB * 64;
    float* ubc        = ws + o; o += (size_t)RREL * BB;
    float* score2     = ws + o; o += (size_t)BB * KK;
    if (ws_size < o * sizeof(float)) return;   // undersized scratch: bail cleanly

    size_t zero_zone = (size_t)RREL * BB * 64 * 2 + RREL * BB + BB * KK;

    // phase 0: init
    hipMemsetAsync(user_slot, 0xFF, (size_t)NUSERS * 4, stream);          // = -1
    hipMemsetAsync(iflag, 0, (size_t)NITEMS * 4, stream);
    hipMemsetAsync(acc_neigh, 0, zero_zone * 4, stream);
    hipMemsetAsync(out + (out_size - 1), 0, 4, stream);                   // l2 slot
    scatter_maps<<<(BB * KK + 255) / 256, 256, 0, stream>>>(user, item, user_slot, iflag);

    // phase 1: atomic-free coarse bucketing (rank-based two-pass)
    pass1_count<<<NBLK, BTH, 0, stream>>>(ig_rows, train_cols, pcnt);
    scan_tot<<<(NBINS + 255) / 256, 256, 0, stream>>>(pcnt, tot);
    scan_bins<<<1, 1024, 0, stream>>>(tot, binbase);
    scan_obase<<<(NBINS + 255) / 256, 256, 0, stream>>>(pcnt, binbase, obase);
    pass2_scatter<<<NBLK, BTH, 0, stream>>>(ig_rows, ig_cols, ig_vals, train_rows, train_cols,
                                            obase, bcol, bval);

    // phase 2: per relation
    for (int i = 0; i < RREL; i++) {
        ig_gather_lds<<<NBIN_SEG, 256, 0, stream>>>(item_emb, binbase, bcol, bval,
                                                    Wp + (size_t)i * 64 * 64, item_prop2, i);
        rel_scan<<<2048, 256, 0, stream>>>(rel_rows + (size_t)i * NNZ_, rel_cols + (size_t)i * NNZ_,
                                           user_slot, item_emb, item_prop2,
                                           acc_neigh + (size_t)i * BB * 64,
                                           acc_prop + (size_t)i * BB * 64, ubc + (size_t)i * BB);
        proj_score2<<<BB, 256, 0, stream>>>(user, user_slot, ubc + (size_t)i * BB,
                                            acc_neigh + (size_t)i * BB * 64,
                                            acc_prop + (size_t)i * BB * 64,
                                            Wb + (size_t)i * 128 * 128,
                                            item, item_emb, item_prop2, score2);
    }

    // phase 3: item_feature via LDS gather, fused @W (itf2 reuses prop2 buffer)
    float* itf2 = item_prop2;
    train_gather_lds<<<NBIN_SEG, 256, 0, stream>>>(user_emb, binbase, bcol, iflag, W, itf2);
    final_k<<<BB, 256, 0, stream>>>(user, item, user_slot, ubc, acc_neigh, mw, W,
                                    user_emb, item_emb, itf2, score2,
                                    out, out + (out_size - 1));
}

// Round 6
// 702.395 us; speedup vs baseline: 2.7347x; 2.7347x over previous
//
#include <hip/hip_runtime.h>

#define EPSF     1e-8f
#define LAMBF    0.5f
#define L2NORMF  1e-4f
#define NUSERS   100000
#define NITEMS   50000
#define EMB      64
#define RREL     3
#define NNZ_     1000000
#define IGNNZ    500000
#define BB       512
#define KK       100

#define IGTOT    (RREL * IGNNZ)               // 1.5M
#define TOTE     (IGTOT + NNZ_)               // 2.5M edges total
#define NBIN_SEG 782                          // ceil(50000/64)
#define NBINS    (4 * NBIN_SEG)               // 3128 coarse bins
#define NBLK     128                          // bucketing blocks
#define BTH      1024                         // bucketing block size
#define SLICE    ((TOTE + NBLK - 1) / NBLK)   // 19532
#define CAPE     2048                         // LDS stage capacity (avg bin: ig 640, train 1279)

// user -> batch slot map + batch-item flags
__global__ void scatter_maps(const int* __restrict__ user, const int* __restrict__ item,
                             int* __restrict__ slot, int* __restrict__ iflag) {
    int i = blockIdx.x * blockDim.x + threadIdx.x;
    if (i < BB) slot[user[i]] = i;
    if (i < BB * KK) iflag[item[i]] = 1;
}

__device__ __forceinline__ int edge_bin(int i, const int* ig_rows, const int* train_cols) {
    if (i < IGTOT) return (i / IGNNZ) * NBIN_SEG + (ig_rows[i] >> 6);
    return 3 * NBIN_SEG + (train_cols[i - IGTOT] >> 6);
}

// pass 1: per-block LDS histogram over coarse bins -> pcnt[block][bin] (plain writes)
__global__ void pass1_count(const int* __restrict__ ig_rows, const int* __restrict__ train_cols,
                            int* __restrict__ pcnt) {
    __shared__ int h[NBINS];
    int b = blockIdx.x, t = threadIdx.x;
    for (int i = t; i < NBINS; i += BTH) h[i] = 0;
    __syncthreads();
    int s = b * SLICE, e = min(s + SLICE, TOTE);
    for (int i = s + t; i < e; i += BTH)
        atomicAdd(&h[edge_bin(i, ig_rows, train_cols)], 1);
    __syncthreads();
    for (int i = t; i < NBINS; i += BTH) pcnt[b * NBINS + i] = h[i];
}

// tot[bin] = sum over blocks (coalesced)
__global__ void scan_tot(const int* __restrict__ pcnt, int* __restrict__ tot) {
    int bin = blockIdx.x * blockDim.x + threadIdx.x;
    if (bin >= NBINS) return;
    int s = 0;
    for (int b = 0; b < NBLK; b++) s += pcnt[b * NBINS + bin];
    tot[bin] = s;
}

// exclusive scan of tot[NBINS] -> binbase (single block)
__global__ void scan_bins(const int* __restrict__ tot, int* __restrict__ binbase) {
    __shared__ int csum[1024];
    int t = threadIdx.x;
    int base = t * 4;
    int v0 = (base + 0 < NBINS) ? tot[base + 0] : 0;
    int v1 = (base + 1 < NBINS) ? tot[base + 1] : 0;
    int v2 = (base + 2 < NBINS) ? tot[base + 2] : 0;
    int v3 = (base + 3 < NBINS) ? tot[base + 3] : 0;
    int s = v0 + v1 + v2 + v3;
    csum[t] = s;
    __syncthreads();
    for (int d = 1; d < 1024; d <<= 1) {
        int x = (t >= d) ? csum[t - d] : 0;
        __syncthreads();
        csum[t] += x;
        __syncthreads();
    }
    int run = csum[t] - s;   // exclusive
    if (base + 0 < NBINS) { binbase[base + 0] = run; run += v0; }
    if (base + 1 < NBINS) { binbase[base + 1] = run; run += v1; }
    if (base + 2 < NBINS) { binbase[base + 2] = run; run += v2; }
    if (base + 3 < NBINS) { binbase[base + 3] = run; run += v3; }
    if (t == 0) binbase[NBINS] = TOTE;
}

// per-(block,bin) base offsets (coalesced across bin)
__global__ void scan_obase(const int* __restrict__ pcnt, const int* __restrict__ binbase,
                           int* __restrict__ obase) {
    int bin = blockIdx.x * blockDim.x + threadIdx.x;
    if (bin >= NBINS) return;
    int run = binbase[bin];
    for (int b = 0; b < NBLK; b++) {
        obase[b * NBINS + bin] = run;
        run += pcnt[b * NBINS + bin];
    }
}

// pass 2: place edges into coarse-bin order; rank via LDS counters seeded with obase
// gcol = (src<<6)|dest_low ; gval (ig edges only)
__global__ void pass2_scatter(const int* __restrict__ ig_rows, const int* __restrict__ ig_cols,
                              const float* __restrict__ ig_vals, const int* __restrict__ train_rows,
                              const int* __restrict__ train_cols, const int* __restrict__ obase,
                              int* __restrict__ gcol, float* __restrict__ gval) {
    __shared__ int pos[NBINS];
    int b = blockIdx.x, t = threadIdx.x;
    for (int i = t; i < NBINS; i += BTH) pos[i] = obase[b * NBINS + i];
    __syncthreads();
    int s = b * SLICE, e = min(s + SLICE, TOTE);
    for (int i = s + t; i < e; i += BTH) {
        if (i < IGTOT) {
            int dest = ig_rows[i];
            int bin = (i / IGNNZ) * NBIN_SEG + (dest >> 6);
            int slot = atomicAdd(&pos[bin], 1);
            gcol[slot] = (ig_cols[i] << 6) | (dest & 63);
            gval[slot] = ig_vals[i];
        } else {
            int e2 = i - IGTOT;
            int dest = train_cols[e2];
            int bin = 3 * NBIN_SEG + (dest >> 6);
            int slot = atomicAdd(&pos[bin], 1);
            gcol[slot] = (train_rows[e2] << 6) | (dest & 63);
        }
    }
}

// ig: block per 64-dest bin. LDS sort by dest, wave-per-dest masked 8-deep gather,
// normalize by deg, fused @Wp via shfl-transpose -> prop2
__global__ void ig_bin_gather(const float* __restrict__ item_emb, const int* __restrict__ binbase,
                              const int* __restrict__ gcol, const float* __restrict__ gval,
                              const float* __restrict__ Wp, float* __restrict__ prop2, int seg) {
    __shared__ int scol[CAPE];
    __shared__ float sval[CAPE];
    __shared__ int cnt[64], off[65], pos[64];
    int t = threadIdx.x, w = t >> 6, lane = t & 63;
    int bin = seg * NBIN_SEG + blockIdx.x;
    int bstart = binbase[bin], bend = binbase[bin + 1];
    int n = bend - bstart;
    int row0 = blockIdx.x * 64;
    if (n <= CAPE) {
        if (t < 64) cnt[t] = 0;
        __syncthreads();
        for (int i = t; i < n; i += 256) atomicAdd(&cnt[gcol[bstart + i] & 63], 1);
        __syncthreads();
        if (t == 0) {
            int run = 0;
            for (int j = 0; j < 64; j++) { off[j] = run; run += cnt[j]; }
            off[64] = run;
        }
        __syncthreads();
        if (t < 64) pos[t] = off[t];
        __syncthreads();
        for (int i = t; i < n; i += 256) {
            int p = gcol[bstart + i];
            int sl = atomicAdd(&pos[p & 63], 1);
            scol[sl] = p >> 6;
            sval[sl] = gval[bstart + i];
        }
        __syncthreads();
        for (int r = w; r < 64; r += 4) {
            int grow = row0 + r;
            if (grow >= NITEMS) break;
            int s = off[r], e = off[r + 1];
            float acc = 0.f, deg = 0.f;
            for (int k = s; k < e; k += 8) {
                int i0 = min(k + 0, e - 1), i1 = min(k + 1, e - 1);
                int i2 = min(k + 2, e - 1), i3 = min(k + 3, e - 1);
                int i4 = min(k + 4, e - 1), i5 = min(k + 5, e - 1);
                int i6 = min(k + 6, e - 1), i7 = min(k + 7, e - 1);
                int c0 = scol[i0], c1 = scol[i1], c2 = scol[i2], c3 = scol[i3];
                int c4 = scol[i4], c5 = scol[i5], c6 = scol[i6], c7 = scol[i7];
                float v0 = (k + 0 < e) ? sval[i0] : 0.f, v1 = (k + 1 < e) ? sval[i1] : 0.f;
                float v2 = (k + 2 < e) ? sval[i2] : 0.f, v3 = (k + 3 < e) ? sval[i3] : 0.f;
                float v4 = (k + 4 < e) ? sval[i4] : 0.f, v5 = (k + 5 < e) ? sval[i5] : 0.f;
                float v6 = (k + 6 < e) ? sval[i6] : 0.f, v7 = (k + 7 < e) ? sval[i7] : 0.f;
                float f0 = item_emb[c0 * 64 + lane], f1 = item_emb[c1 * 64 + lane];
                float f2 = item_emb[c2 * 64 + lane], f3 = item_emb[c3 * 64 + lane];
                float f4 = item_emb[c4 * 64 + lane], f5 = item_emb[c5 * 64 + lane];
                float f6 = item_emb[c6 * 64 + lane], f7 = item_emb[c7 * 64 + lane];
                acc += v0 * f0 + v1 * f1 + v2 * f2 + v3 * f3
                     + v4 * f4 + v5 * f5 + v6 * f6 + v7 * f7;
                deg += (v0 + v1 + v2 + v3) + (v4 + v5 + v6 + v7);
            }
            float av = acc / (deg + EPSF);
            float o = 0.f;
#pragma unroll 8
            for (int k2 = 0; k2 < 64; k2++) o += __shfl(av, k2) * Wp[k2 * 64 + lane];
            prop2[grow * 64 + lane] = o;
        }
    } else {
        // slow fallback (bin > CAPE; statistically never for this input)
        for (int r = w; r < 64; r += 4) {
            int grow = row0 + r;
            if (grow >= NITEMS) break;
            float acc = 0.f, deg = 0.f;
            for (int j0 = bstart; j0 < bend; j0 += 64) {
                int j = j0 + lane;
                int p = (j < bend) ? gcol[j] : -1;
                float v = (j < bend) ? gval[j] : 0.f;
                unsigned long long mask = __ballot(p >= 0 && (p & 63) == r);
                while (mask) {
                    int jj = __builtin_ctzll(mask); mask &= mask - 1;
                    int pj = __shfl(p, jj);
                    float vj = __shfl(v, jj);
                    acc += vj * item_emb[(pj >> 6) * 64 + lane];
                    deg += vj;
                }
            }
            float av = acc / (deg + EPSF);
            float o = 0.f;
#pragma unroll 8
            for (int k2 = 0; k2 < 64; k2++) o += __shfl(av, k2) * Wp[k2 * 64 + lane];
            prop2[grow * 64 + lane] = o;
        }
    }
}

// train: block per 64-dest bin, iflag-gated, fused @W -> itf2 (no vals)
__global__ void train_bin_gather(const float* __restrict__ user_emb, const int* __restrict__ binbase,
                                 const int* __restrict__ gcol, const int* __restrict__ iflag,
                                 const float* __restrict__ Wm, float* __restrict__ itf2) {
    __shared__ int scol[CAPE];
    __shared__ int cnt[64], off[65], pos[64];
    int t = threadIdx.x, w = t >> 6, lane = t & 63;
    int bin = 3 * NBIN_SEG + blockIdx.x;
    int bstart = binbase[bin], bend = binbase[bin + 1];
    int n = bend - bstart;
    int row0 = blockIdx.x * 64;
    if (n <= CAPE) {
        if (t < 64) cnt[t] = 0;
        __syncthreads();
        for (int i = t; i < n; i += 256) atomicAdd(&cnt[gcol[bstart + i] & 63], 1);
        __syncthreads();
        if (t == 0) {
            int run = 0;
            for (int j = 0; j < 64; j++) { off[j] = run; run += cnt[j]; }
            off[64] = run;
        }
        __syncthreads();
        if (t < 64) pos[t] = off[t];
        __syncthreads();
        for (int i = t; i < n; i += 256) {
            int p = gcol[bstart + i];
            int sl = atomicAdd(&pos[p & 63], 1);
            scol[sl] = p >> 6;
        }
        __syncthreads();
        for (int r = w; r < 64; r += 4) {
            int grow = row0 + r;
            if (grow >= NITEMS) break;
            if (!iflag[grow]) continue;
            int s = off[r], e = off[r + 1];
            float acc = 0.f;
            for (int k = s; k < e; k += 8) {
                int i0 = min(k + 0, e - 1), i1 = min(k + 1, e - 1);
                int i2 = min(k + 2, e - 1), i3 = min(k + 3, e - 1);
                int i4 = min(k + 4, e - 1), i5 = min(k + 5, e - 1);
                int i6 = min(k + 6, e - 1), i7 = min(k + 7, e - 1);
                int c0 = scol[i0], c1 = scol[i1], c2 = scol[i2], c3 = scol[i3];
                int c4 = scol[i4], c5 = scol[i5], c6 = scol[i6], c7 = scol[i7];
                float m1 = (k + 1 < e) ? 1.f : 0.f, m2 = (k + 2 < e) ? 1.f : 0.f;
                float m3 = (k + 3 < e) ? 1.f : 0.f, m4 = (k + 4 < e) ? 1.f : 0.f;
                float m5 = (k + 5 < e) ? 1.f : 0.f, m6 = (k + 6 < e) ? 1.f : 0.f;
                float m7 = (k + 7 < e) ? 1.f : 0.f;
                float f0 = user_emb[c0 * 64 + lane], f1 = user_emb[c1 * 64 + lane];
                float f2 = user_emb[c2 * 64 + lane], f3 = user_emb[c3 * 64 + lane];
                float f4 = user_emb[c4 * 64 + lane], f5 = user_emb[c5 * 64 + lane];
                float f6 = user_emb[c6 * 64 + lane], f7 = user_emb[c7 * 64 + lane];
                acc += f0 + m1 * f1 + m2 * f2 + m3 * f3
                     + m4 * f4 + m5 * f5 + m6 * f6 + m7 * f7;
            }
            float o = 0.f;
#pragma unroll 8
            for (int k2 = 0; k2 < 64; k2++) o += __shfl(acc, k2) * Wm[k2 * 64 + lane];
            itf2[grow * 64 + lane] = o;
        }
    } else {
        for (int r = w; r < 64; r += 4) {
            int grow = row0 + r;
            if (grow >= NITEMS) break;
            if (!iflag[grow]) continue;
            float acc = 0.f;
            for (int j0 = bstart; j0 < bend; j0 += 64) {
                int j = j0 + lane;
                int p = (j < bend) ? gcol[j] : -1;
                unsigned long long mask = __ballot(p >= 0 && (p & 63) == r);
                while (mask) {
                    int jj = __builtin_ctzll(mask); mask &= mask - 1;
                    int pj = __shfl(p, jj);
                    acc += user_emb[(pj >> 6) * 64 + lane];
                }
            }
            float o = 0.f;
#pragma unroll 8
            for (int k2 = 0; k2 < 64; k2++) o += __shfl(acc, k2) * Wm[k2 * 64 + lane];
            itf2[grow * 64 + lane] = o;
        }
    }
}

__device__ __forceinline__ void rel_hit(int s, int c, int lane,
                                        const float* __restrict__ item_emb,
                                        const float* __restrict__ prop2,
                                        float* __restrict__ accN, float* __restrict__ accP,
                                        float* __restrict__ ubc) {
    unsigned long long mask = __ballot(s >= 0);
    while (mask) {
        int j = __builtin_ctzll(mask);
        mask &= mask - 1;
        int bs = __shfl(s, j);
        int bc = __shfl(c, j);
        atomicAdd(&accN[bs * EMB + lane], item_emb[bc * EMB + lane]);
        atomicAdd(&accP[bs * EMB + lane], prop2[bc * EMB + lane]);
        if (lane == 0) atomicAdd(&ubc[bs], 1.0f);
    }
}

// filtered relation scan (int4 per lane = 256 edges/wave/iter)
__global__ void rel_scan(const int* __restrict__ rows, const int* __restrict__ cols,
                         const int* __restrict__ slot, const float* __restrict__ item_emb,
                         const float* __restrict__ prop2,
                         float* __restrict__ accN, float* __restrict__ accP,
                         float* __restrict__ ubc) {
    int lane = threadIdx.x & 63;
    int gw = (blockIdx.x * blockDim.x + threadIdx.x) >> 6;
    int nw = (gridDim.x * blockDim.x) >> 6;
    for (int ch = gw; ch < NNZ_ / 256; ch += nw) {
        int base = ch * 256 + lane * 4;
        int4 r4 = *reinterpret_cast<const int4*>(rows + base);
        int4 c4 = *reinterpret_cast<const int4*>(cols + base);
        int s0 = slot[r4.x], s1 = slot[r4.y], s2 = slot[r4.z], s3 = slot[r4.w];
        rel_hit(s0, c4.x, lane, item_emb, prop2, accN, accP, ubc);
        rel_hit(s1, c4.y, lane, item_emb, prop2, accN, accP, ubc);
        rel_hit(s2, c4.z, lane, item_emb, prop2, accN, accP, ubc);
        rel_hit(s3, c4.w, lane, item_emb, prop2, accN, accP, ubc);
    }
}

// per batch row: proj = tmp_user_item_p[user[b]] @ Wb, then
// score2[b,k] += dot(proj, [item_emb[it] | prop2[it]])
__global__ void proj_score2(const int* __restrict__ user, const int* __restrict__ slot,
                            const float* __restrict__ ubc, const float* __restrict__ acc_neigh,
                            const float* __restrict__ acc_prop, const float* __restrict__ Wb,
                            const int* __restrict__ item, const float* __restrict__ item_emb,
                            const float* __restrict__ item_prop2, float* __restrict__ score2) {
    int b = blockIdx.x;
    int tid = threadIdx.x;               // 256
    __shared__ float tbuf[128];
    __shared__ float p[128];
    int rep = slot[user[b]];
    float inv = 1.0f / (ubc[rep] + EPSF);
    if (tid < 64)       tbuf[tid] = acc_neigh[rep * 64 + tid] * inv;
    else if (tid < 128) tbuf[tid] = acc_prop[rep * 64 + (tid - 64)] * inv;
    __syncthreads();
    if (tid < 128) {
        float o = 0.f;
#pragma unroll 8
        for (int k = 0; k < 128; k++) o += tbuf[k] * Wb[k * 128 + tid];
        p[tid] = o;
    }
    __syncthreads();
    int wave = tid >> 6, lane = tid & 63;
    for (int k = wave; k < KK; k += 4) {
        int it = item[b * KK + k];
        float s = p[lane] * item_emb[it * 64 + lane] + p[64 + lane] * item_prop2[it * 64 + lane];
        for (int off = 32; off > 0; off >>= 1) s += __shfl_xor(s, off);
        if (lane == 0) score2[b * KK + k] += s;
    }
}

// final: ufeat + @W in-block, then score1 + LAMB*score2/R + l2
__global__ void final_k(const int* __restrict__ user, const int* __restrict__ item,
                        const int* __restrict__ slot, const float* __restrict__ ubc,
                        const float* __restrict__ acc_neigh, const float* __restrict__ mw,
                        const float* __restrict__ W, const float* __restrict__ user_emb,
                        const float* __restrict__ item_emb, const float* __restrict__ itf2,
                        const float* __restrict__ score2, float* __restrict__ out,
                        float* __restrict__ l2out) {
    int b = blockIdx.x;
    int tid = threadIdx.x;               // 256
    int wave = tid >> 6, lane = tid & 63;
    __shared__ float uf[64], u1[64], u2[64];
    __shared__ float red[4];
    int u = user[b];
    if (tid < 64) {
        int rep = slot[u];
        float w0 = mw[0], w1 = mw[1], w2 = mw[2];
        float c0 = ubc[0 * BB + rep], c1 = ubc[1 * BB + rep], c2 = ubc[2 * BB + rep];
        float invT = 1.0f / (c0 * w0 + c1 * w1 + c2 * w2 + EPSF);
        float f = (c0 * w0 * invT) / (c0 + EPSF) * acc_neigh[(0 * BB + rep) * 64 + tid]
                + (c1 * w1 * invT) / (c1 + EPSF) * acc_neigh[(1 * BB + rep) * 64 + tid]
                + (c2 * w2 * invT) / (c2 + EPSF) * acc_neigh[(2 * BB + rep) * 64 + tid];
        uf[tid] = f;
        u1[tid] = user_emb[u * 64 + tid];
    }
    __syncthreads();
    if (tid < 64) {
        float o = 0.f;
#pragma unroll
        for (int k = 0; k < 64; k++) o += uf[k] * W[k * 64 + tid];
        u2[tid] = o;
    }
    __syncthreads();
    float l2part = 0.f;
    for (int k = wave; k < KK; k += 4) {
        int it = item[b * KK + k];
        float e1 = item_emb[it * 64 + lane], e2 = itf2[it * 64 + lane];
        float s = u1[lane] * e1 + u2[lane] * e2;
        float q = e1 * e1 + e2 * e2;
        for (int off = 32; off > 0; off >>= 1) {
            s += __shfl_xor(s, off);
            q += __shfl_xor(q, off);
        }
        if (lane == 0) {
            out[b * KK + k] = s + LAMBF * (score2[b * KK + k] * (1.0f / (float)RREL));
            l2part += q;
        }
    }
    float su = u1[lane] * u1[lane] + u2[lane] * u2[lane];
    for (int off = 32; off > 0; off >>= 1) su += __shfl_xor(su, off);
    if (wave == 0 && lane == 0) l2part += (float)KK * su;
    if (lane == 0) red[wave] = l2part;
    __syncthreads();
    if (tid == 0) atomicAdd(l2out, L2NORMF * (red[0] + red[1] + red[2] + red[3]));
}

extern "C" void kernel_launch(void* const* d_in, const int* in_sizes, int n_in,
                              void* d_out, int out_size, void* d_ws, size_t ws_size,
                              hipStream_t stream) {
    const int*   user       = (const int*)d_in[0];
    const int*   item       = (const int*)d_in[1];
    const int*   rel_rows   = (const int*)d_in[2];
    const int*   rel_cols   = (const int*)d_in[3];
    const int*   ig_rows    = (const int*)d_in[4];
    const int*   ig_cols    = (const int*)d_in[5];
    const float* ig_vals    = (const float*)d_in[6];
    const int*   train_rows = (const int*)d_in[7];
    const int*   train_cols = (const int*)d_in[8];
    const float* user_emb   = (const float*)d_in[9];
    const float* item_emb   = (const float*)d_in[10];
    const float* mw         = (const float*)d_in[11];
    const float* Wb         = (const float*)d_in[12];  // R x 128 x 128
    const float* Wp         = (const float*)d_in[13];  // R x 64 x 64
    const float* W          = (const float*)d_in[14];  // 64 x 64
    float* out = (float*)d_out;

    // ---- workspace layout (4-byte words) ----
    float* ws = (float*)d_ws;
    size_t o = 0;
    int*   user_slot  = (int*)(ws + o); o += NUSERS;          // memset 0xFF
    int*   iflag      = (int*)(ws + o); o += NITEMS;          // memset 0
    int*   pcnt       = (int*)(ws + o); o += (size_t)NBLK * NBINS;
    int*   tot        = (int*)(ws + o); o += NBINS;
    int*   binbase    = (int*)(ws + o); o += NBINS + 1;
    int*   obase      = (int*)(ws + o); o += (size_t)NBLK * NBINS;
    int*   gcol       = (int*)(ws + o); o += TOTE;
    float* gval       = ws + o; o += IGTOT;
    float* item_prop2 = ws + o; o += (size_t)NITEMS * 64;     // reused as itf2 at the end
    // contiguous zero zone:
    float* acc_neigh  = ws + o; o += (size_t)RREL * BB * 64;
    float* acc_prop   = ws + o; o += (size_t)RREL * BB * 64;
    float* ubc        = ws + o; o += (size_t)RREL * BB;
    float* score2     = ws + o; o += (size_t)BB * KK;
    if (ws_size < o * sizeof(float)) return;   // undersized scratch: bail cleanly

    size_t zero_zone = (size_t)RREL * BB * 64 * 2 + RREL * BB + BB * KK;

    // phase 0: init
    hipMemsetAsync(user_slot, 0xFF, (size_t)NUSERS * 4, stream);          // = -1
    hipMemsetAsync(iflag, 0, (size_t)NITEMS * 4, stream);
    hipMemsetAsync(acc_neigh, 0, zero_zone * 4, stream);
    hipMemsetAsync(out + (out_size - 1), 0, 4, stream);                   // l2 slot
    scatter_maps<<<(BB * KK + 255) / 256, 256, 0, stream>>>(user, item, user_slot, iflag);

    // phase 1: atomic-free coarse bucketing (rank-based two-pass)
    pass1_count<<<NBLK, BTH, 0, stream>>>(ig_rows, train_cols, pcnt);
    scan_tot<<<(NBINS + 255) / 256, 256, 0, stream>>>(pcnt, tot);
    scan_bins<<<1, 1024, 0, stream>>>(tot, binbase);
    scan_obase<<<(NBINS + 255) / 256, 256, 0, stream>>>(pcnt, binbase, obase);
    pass2_scatter<<<NBLK, BTH, 0, stream>>>(ig_rows, ig_cols, ig_vals, train_rows, train_cols,
                                            obase, gcol, gval);

    // phase 2: per relation
    for (int i = 0; i < RREL; i++) {
        ig_bin_gather<<<NBIN_SEG, 256, 0, stream>>>(item_emb, binbase, gcol, gval,
                                                    Wp + (size_t)i * 64 * 64, item_prop2, i);
        rel_scan<<<1024, 256, 0, stream>>>(rel_rows + (size_t)i * NNZ_, rel_cols + (size_t)i * NNZ_,
                                           user_slot, item_emb, item_prop2,
                                           acc_neigh + (size_t)i * BB * 64,
                                           acc_prop + (size_t)i * BB * 64, ubc + (size_t)i * BB);
        proj_score2<<<BB, 256, 0, stream>>>(user, user_slot, ubc + (size_t)i * BB,
                                            acc_neigh + (size_t)i * BB * 64,
                                            acc_prop + (size_t)i * BB * 64,
                                            Wb + (size_t)i * 128 * 128,
                                            item, item_emb, item_prop2, score2);
    }

    // phase 3: item_feature via bin gather, fused @W (itf2 reuses prop2 buffer)
    float* itf2 = item_prop2;
    train_bin_gather<<<NBIN_SEG, 256, 0, stream>>>(user_emb, binbase, gcol, iflag, W, itf2);
    final_k<<<BB, 256, 0, stream>>>(user, item, user_slot, ubc, acc_neigh, mw, W,
                                    user_emb, item_emb, itf2, score2,
                                    out, out + (out_size - 1));
}

// Round 9
// 632.440 us; speedup vs baseline: 3.0372x; 1.1106x over previous
//
#include <hip/hip_runtime.h>

#define EPSF     1e-8f
#define LAMBF    0.5f
#define L2NORMF  1e-4f
#define NUSERS   100000
#define NITEMS   50000
#define EMB      64
#define RREL     3
#define NNZ_     1000000
#define IGNNZ    500000
#define BB       512
#define KK       100

#define IGTOT    (RREL * IGNNZ)               // 1.5M
#define TOTE     (IGTOT + NNZ_)               // 2.5M edges total
#define NBIN_SEG 782                          // ceil(50000/64)
#define NBINS    (4 * NBIN_SEG)               // 3128 coarse bins
#define NBLK     128                          // bucketing blocks
#define BTH      1024                         // bucketing block size
#define SLICE    ((TOTE + NBLK - 1) / NBLK)   // 19532
#define CAPE     2048                         // LDS stage capacity (avg bin: ig 640, train 1279)
#define GTH      512                          // gather block size (8 waves)

// user -> batch slot map + batch-item flags
__global__ void scatter_maps(const int* __restrict__ user, const int* __restrict__ item,
                             int* __restrict__ slot, int* __restrict__ iflag) {
    int i = blockIdx.x * blockDim.x + threadIdx.x;
    if (i < BB) slot[user[i]] = i;
    if (i < BB * KK) iflag[item[i]] = 1;
}

__device__ __forceinline__ int edge_bin(int i, const int* ig_rows, const int* train_cols) {
    if (i < IGTOT) return (i / IGNNZ) * NBIN_SEG + (ig_rows[i] >> 6);
    return 3 * NBIN_SEG + (train_cols[i - IGTOT] >> 6);
}

// pass 1: per-block LDS histogram over coarse bins -> pcnt[block][bin] (plain writes)
__global__ void pass1_count(const int* __restrict__ ig_rows, const int* __restrict__ train_cols,
                            int* __restrict__ pcnt) {
    __shared__ int h[NBINS];
    int b = blockIdx.x, t = threadIdx.x;
    for (int i = t; i < NBINS; i += BTH) h[i] = 0;
    __syncthreads();
    int s = b * SLICE, e = min(s + SLICE, TOTE);
    for (int i = s + t; i < e; i += BTH)
        atomicAdd(&h[edge_bin(i, ig_rows, train_cols)], 1);
    __syncthreads();
    for (int i = t; i < NBINS; i += BTH) pcnt[b * NBINS + i] = h[i];
}

// tot[bin] = sum over blocks (coalesced)
__global__ void scan_tot(const int* __restrict__ pcnt, int* __restrict__ tot) {
    int bin = blockIdx.x * blockDim.x + threadIdx.x;
    if (bin >= NBINS) return;
    int s = 0;
    for (int b = 0; b < NBLK; b++) s += pcnt[b * NBINS + bin];
    tot[bin] = s;
}

// exclusive scan of tot[NBINS] -> binbase (single block)
__global__ void scan_bins(const int* __restrict__ tot, int* __restrict__ binbase) {
    __shared__ int csum[1024];
    int t = threadIdx.x;
    int base = t * 4;
    int v0 = (base + 0 < NBINS) ? tot[base + 0] : 0;
    int v1 = (base + 1 < NBINS) ? tot[base + 1] : 0;
    int v2 = (base + 2 < NBINS) ? tot[base + 2] : 0;
    int v3 = (base + 3 < NBINS) ? tot[base + 3] : 0;
    int s = v0 + v1 + v2 + v3;
    csum[t] = s;
    __syncthreads();
    for (int d = 1; d < 1024; d <<= 1) {
        int x = (t >= d) ? csum[t - d] : 0;
        __syncthreads();
        csum[t] += x;
        __syncthreads();
    }
    int run = csum[t] - s;   // exclusive
    if (base + 0 < NBINS) { binbase[base + 0] = run; run += v0; }
    if (base + 1 < NBINS) { binbase[base + 1] = run; run += v1; }
    if (base + 2 < NBINS) { binbase[base + 2] = run; run += v2; }
    if (base + 3 < NBINS) { binbase[base + 3] = run; run += v3; }
    if (t == 0) binbase[NBINS] = TOTE;
}

// per-(block,bin) base offsets (coalesced across bin)
__global__ void scan_obase(const int* __restrict__ pcnt, const int* __restrict__ binbase,
                           int* __restrict__ obase) {
    int bin = blockIdx.x * blockDim.x + threadIdx.x;
    if (bin >= NBINS) return;
    int run = binbase[bin];
    for (int b = 0; b < NBLK; b++) {
        obase[b * NBINS + bin] = run;
        run += pcnt[b * NBINS + bin];
    }
}

// pass 2: place edges; rank via LDS counters seeded with obase (no global atomics)
// ig edges: single int2 {(col<<6)|dlow, bits(val)} -> garr[slot]
// train edges: int (user<<6)|dlow -> tcol[slot - IGTOT]
__global__ void pass2_scatter(const int* __restrict__ ig_rows, const int* __restrict__ ig_cols,
                              const float* __restrict__ ig_vals, const int* __restrict__ train_rows,
                              const int* __restrict__ train_cols, const int* __restrict__ obase,
                              int2* __restrict__ garr, int* __restrict__ tcol) {
    __shared__ int pos[NBINS];
    int b = blockIdx.x, t = threadIdx.x;
    for (int i = t; i < NBINS; i += BTH) pos[i] = obase[b * NBINS + i];
    __syncthreads();
    int s = b * SLICE, e = min(s + SLICE, TOTE);
    for (int i = s + t; i < e; i += BTH) {
        if (i < IGTOT) {
            int dest = ig_rows[i];
            int bin = (i / IGNNZ) * NBIN_SEG + (dest >> 6);
            int slot = atomicAdd(&pos[bin], 1);
            garr[slot] = make_int2((ig_cols[i] << 6) | (dest & 63),
                                   __float_as_int(ig_vals[i]));
        } else {
            int e2 = i - IGTOT;
            int dest = train_cols[e2];
            int bin = 3 * NBIN_SEG + (dest >> 6);
            int slot = atomicAdd(&pos[bin], 1);
            tcol[slot - IGTOT] = (train_rows[e2] << 6) | (dest & 63);
        }
    }
}

// ig: block (512 thr, 8 waves) per 64-dest bin. LDS sort by dest, wave-per-dest
// masked 8-deep gather, normalize by deg, fused @Wp via shfl-transpose -> prop2
__global__ void ig_bin_gather(const float* __restrict__ item_emb, const int* __restrict__ binbase,
                              const int2* __restrict__ garr, const float* __restrict__ Wp,
                              float* __restrict__ prop2, int seg) {
    __shared__ int scol[CAPE];
    __shared__ float sval[CAPE];
    __shared__ int cnt[64], off[65], pos[64];
    int t = threadIdx.x, w = t >> 6, lane = t & 63;
    int bin = seg * NBIN_SEG + blockIdx.x;
    int bstart = binbase[bin], bend = binbase[bin + 1];
    int n = bend - bstart;
    int row0 = blockIdx.x * 64;
    if (n <= CAPE) {
        if (t < 64) cnt[t] = 0;
        __syncthreads();
        for (int i = t; i < n; i += GTH) atomicAdd(&cnt[garr[bstart + i].x & 63], 1);
        __syncthreads();
        if (t == 0) {
            int run = 0;
            for (int j = 0; j < 64; j++) { off[j] = run; run += cnt[j]; }
            off[64] = run;
        }
        __syncthreads();
        if (t < 64) pos[t] = off[t];
        __syncthreads();
        for (int i = t; i < n; i += GTH) {
            int2 pv = garr[bstart + i];
            int sl = atomicAdd(&pos[pv.x & 63], 1);
            scol[sl] = pv.x >> 6;
            sval[sl] = __int_as_float(pv.y);
        }
        __syncthreads();
        for (int r = w; r < 64; r += 8) {
            int grow = row0 + r;
            if (grow >= NITEMS) break;
            int s = off[r], e = off[r + 1];
            float acc = 0.f, deg = 0.f;
            for (int k = s; k < e; k += 8) {
                int i0 = min(k + 0, e - 1), i1 = min(k + 1, e - 1);
                int i2 = min(k + 2, e - 1), i3 = min(k + 3, e - 1);
                int i4 = min(k + 4, e - 1), i5 = min(k + 5, e - 1);
                int i6 = min(k + 6, e - 1), i7 = min(k + 7, e - 1);
                int c0 = scol[i0], c1 = scol[i1], c2 = scol[i2], c3 = scol[i3];
                int c4 = scol[i4], c5 = scol[i5], c6 = scol[i6], c7 = scol[i7];
                float v0 = (k + 0 < e) ? sval[i0] : 0.f, v1 = (k + 1 < e) ? sval[i1] : 0.f;
                float v2 = (k + 2 < e) ? sval[i2] : 0.f, v3 = (k + 3 < e) ? sval[i3] : 0.f;
                float v4 = (k + 4 < e) ? sval[i4] : 0.f, v5 = (k + 5 < e) ? sval[i5] : 0.f;
                float v6 = (k + 6 < e) ? sval[i6] : 0.f, v7 = (k + 7 < e) ? sval[i7] : 0.f;
                float f0 = item_emb[c0 * 64 + lane], f1 = item_emb[c1 * 64 + lane];
                float f2 = item_emb[c2 * 64 + lane], f3 = item_emb[c3 * 64 + lane];
                float f4 = item_emb[c4 * 64 + lane], f5 = item_emb[c5 * 64 + lane];
                float f6 = item_emb[c6 * 64 + lane], f7 = item_emb[c7 * 64 + lane];
                acc += v0 * f0 + v1 * f1 + v2 * f2 + v3 * f3
                     + v4 * f4 + v5 * f5 + v6 * f6 + v7 * f7;
                deg += (v0 + v1 + v2 + v3) + (v4 + v5 + v6 + v7);
            }
            float av = acc / (deg + EPSF);
            float o = 0.f;
#pragma unroll 8
            for (int k2 = 0; k2 < 64; k2++) o += __shfl(av, k2) * Wp[k2 * 64 + lane];
            prop2[grow * 64 + lane] = o;
        }
    } else {
        // slow fallback (bin > CAPE; statistically never for this input)
        for (int r = w; r < 64; r += 8) {
            int grow = row0 + r;
            if (grow >= NITEMS) break;
            float acc = 0.f, deg = 0.f;
            for (int j0 = bstart; j0 < bend; j0 += 64) {
                int j = j0 + lane;
                int2 pv = (j < bend) ? garr[j] : make_int2(-1, 0);
                unsigned long long mask = __ballot(pv.x >= 0 && (pv.x & 63) == r);
                while (mask) {
                    int jj = __builtin_ctzll(mask); mask &= mask - 1;
                    int pj = __shfl(pv.x, jj);
                    float vj = __shfl(__int_as_float(pv.y), jj);
                    acc += vj * item_emb[(pj >> 6) * 64 + lane];
                    deg += vj;
                }
            }
            float av = acc / (deg + EPSF);
            float o = 0.f;
#pragma unroll 8
            for (int k2 = 0; k2 < 64; k2++) o += __shfl(av, k2) * Wp[k2 * 64 + lane];
            prop2[grow * 64 + lane] = o;
        }
    }
}

// train: block (512 thr) per 64-dest bin, iflag-gated, fused @W -> itf2
__global__ void train_bin_gather(const float* __restrict__ user_emb, const int* __restrict__ binbase,
                                 const int* __restrict__ tcol, const int* __restrict__ iflag,
                                 const float* __restrict__ Wm, float* __restrict__ itf2) {
    __shared__ int scol[CAPE];
    __shared__ int cnt[64], off[65], pos[64];
    int t = threadIdx.x, w = t >> 6, lane = t & 63;
    int bin = 3 * NBIN_SEG + blockIdx.x;
    int bstart = binbase[bin] - IGTOT, bend = binbase[bin + 1] - IGTOT;
    int n = bend - bstart;
    int row0 = blockIdx.x * 64;
    if (n <= CAPE) {
        if (t < 64) cnt[t] = 0;
        __syncthreads();
        for (int i = t; i < n; i += GTH) atomicAdd(&cnt[tcol[bstart + i] & 63], 1);
        __syncthreads();
        if (t == 0) {
            int run = 0;
            for (int j = 0; j < 64; j++) { off[j] = run; run += cnt[j]; }
            off[64] = run;
        }
        __syncthreads();
        if (t < 64) pos[t] = off[t];
        __syncthreads();
        for (int i = t; i < n; i += GTH) {
            int p = tcol[bstart + i];
            int sl = atomicAdd(&pos[p & 63], 1);
            scol[sl] = p >> 6;
        }
        __syncthreads();
        for (int r = w; r < 64; r += 8) {
            int grow = row0 + r;
            if (grow >= NITEMS) break;
            if (!iflag[grow]) continue;
            int s = off[r], e = off[r + 1];
            float acc = 0.f;
            for (int k = s; k < e; k += 8) {
                int i0 = min(k + 0, e - 1), i1 = min(k + 1, e - 1);
                int i2 = min(k + 2, e - 1), i3 = min(k + 3, e - 1);
                int i4 = min(k + 4, e - 1), i5 = min(k + 5, e - 1);
                int i6 = min(k + 6, e - 1), i7 = min(k + 7, e - 1);
                int c0 = scol[i0], c1 = scol[i1], c2 = scol[i2], c3 = scol[i3];
                int c4 = scol[i4], c5 = scol[i5], c6 = scol[i6], c7 = scol[i7];
                float m1 = (k + 1 < e) ? 1.f : 0.f, m2 = (k + 2 < e) ? 1.f : 0.f;
                float m3 = (k + 3 < e) ? 1.f : 0.f, m4 = (k + 4 < e) ? 1.f : 0.f;
                float m5 = (k + 5 < e) ? 1.f : 0.f, m6 = (k + 6 < e) ? 1.f : 0.f;
                float m7 = (k + 7 < e) ? 1.f : 0.f;
                float f0 = user_emb[c0 * 64 + lane], f1 = user_emb[c1 * 64 + lane];
                float f2 = user_emb[c2 * 64 + lane], f3 = user_emb[c3 * 64 + lane];
                float f4 = user_emb[c4 * 64 + lane], f5 = user_emb[c5 * 64 + lane];
                float f6 = user_emb[c6 * 64 + lane], f7 = user_emb[c7 * 64 + lane];
                acc += f0 + m1 * f1 + m2 * f2 + m3 * f3
                     + m4 * f4 + m5 * f5 + m6 * f6 + m7 * f7;
            }
            float o = 0.f;
#pragma unroll 8
            for (int k2 = 0; k2 < 64; k2++) o += __shfl(acc, k2) * Wm[k2 * 64 + lane];
            itf2[grow * 64 + lane] = o;
        }
    } else {
        for (int r = w; r < 64; r += 8) {
            int grow = row0 + r;
            if (grow >= NITEMS) break;
            if (!iflag[grow]) continue;
            float acc = 0.f;
            for (int j0 = bstart; j0 < bend; j0 += 64) {
                int j = j0 + lane;
                int p = (j < bend) ? tcol[j] : -1;
                unsigned long long mask = __ballot(p >= 0 && (p & 63) == r);
                while (mask) {
                    int jj = __builtin_ctzll(mask); mask &= mask - 1;
                    int pj = __shfl(p, jj);
                    acc += user_emb[(pj >> 6) * 64 + lane];
                }
            }
            float o = 0.f;
#pragma unroll 8
            for (int k2 = 0; k2 < 64; k2++) o += __shfl(acc, k2) * Wm[k2 * 64 + lane];
            itf2[grow * 64 + lane] = o;
        }
    }
}

__device__ __forceinline__ void rel_hit(int s, int c, int lane,
                                        const float* __restrict__ item_emb,
                                        const float* __restrict__ prop2,
                                        float* __restrict__ accN, float* __restrict__ accP,
                                        float* __restrict__ ubc) {
    unsigned long long mask = __ballot(s >= 0);
    while (mask) {
        int j = __builtin_ctzll(mask);
        mask &= mask - 1;
        int bs = __shfl(s, j);
        int bc = __shfl(c, j);
        atomicAdd(&accN[bs * EMB + lane], item_emb[bc * EMB + lane]);
        atomicAdd(&accP[bs * EMB + lane], prop2[bc * EMB + lane]);
        if (lane == 0) atomicAdd(&ubc[bs], 1.0f);
    }
}

// filtered relation scan (int4 per lane = 256 edges/wave/iter)
__global__ void rel_scan(const int* __restrict__ rows, const int* __restrict__ cols,
                         const int* __restrict__ slot, const float* __restrict__ item_emb,
                         const float* __restrict__ prop2,
                         float* __restrict__ accN, float* __restrict__ accP,
                         float* __restrict__ ubc) {
    int lane = threadIdx.x & 63;
    int gw = (blockIdx.x * blockDim.x + threadIdx.x) >> 6;
    int nw = (gridDim.x * blockDim.x) >> 6;
    for (int ch = gw; ch < NNZ_ / 256; ch += nw) {
        int base = ch * 256 + lane * 4;
        int4 r4 = *reinterpret_cast<const int4*>(rows + base);
        int4 c4 = *reinterpret_cast<const int4*>(cols + base);
        int s0 = slot[r4.x], s1 = slot[r4.y], s2 = slot[r4.z], s3 = slot[r4.w];
        rel_hit(s0, c4.x, lane, item_emb, prop2, accN, accP, ubc);
        rel_hit(s1, c4.y, lane, item_emb, prop2, accN, accP, ubc);
        rel_hit(s2, c4.z, lane, item_emb, prop2, accN, accP, ubc);
        rel_hit(s3, c4.w, lane, item_emb, prop2, accN, accP, ubc);
    }
}

// per batch row: proj = tmp_user_item_p[user[b]] @ Wb, then
// score2[b,k] += dot(proj, [item_emb[it] | prop2[it]])
__global__ void proj_score2(const int* __restrict__ user, const int* __restrict__ slot,
                            const float* __restrict__ ubc, const float* __restrict__ acc_neigh,
                            const float* __restrict__ acc_prop, const float* __restrict__ Wb,
                            const int* __restrict__ item, const float* __restrict__ item_emb,
                            const float* __restrict__ item_prop2, float* __restrict__ score2) {
    int b = blockIdx.x;
    int tid = threadIdx.x;               // 256
    __shared__ float tbuf[128];
    __shared__ float p[128];
    int rep = slot[user[b]];
    float inv = 1.0f / (ubc[rep] + EPSF);
    if (tid < 64)       tbuf[tid] = acc_neigh[rep * 64 + tid] * inv;
    else if (tid < 128) tbuf[tid] = acc_prop[rep * 64 + (tid - 64)] * inv;
    __syncthreads();
    if (tid < 128) {
        float o = 0.f;
#pragma unroll 8
        for (int k = 0; k < 128; k++) o += tbuf[k] * Wb[k * 128 + tid];
        p[tid] = o;
    }
    __syncthreads();
    int wave = tid >> 6, lane = tid & 63;
    for (int k = wave; k < KK; k += 4) {
        int it = item[b * KK + k];
        float s = p[lane] * item_emb[it * 64 + lane] + p[64 + lane] * item_prop2[it * 64 + lane];
        for (int off = 32; off > 0; off >>= 1) s += __shfl_xor(s, off);
        if (lane == 0) score2[b * KK + k] += s;
    }
}

// final: ufeat + @W in-block, then score1 + LAMB*score2/R + l2
__global__ void final_k(const int* __restrict__ user, const int* __restrict__ item,
                        const int* __restrict__ slot, const float* __restrict__ ubc,
                        const float* __restrict__ acc_neigh, const float* __restrict__ mw,
                        const float* __restrict__ W, const float* __restrict__ user_emb,
                        const float* __restrict__ item_emb, const float* __restrict__ itf2,
                        const float* __restrict__ score2, float* __restrict__ out,
                        float* __restrict__ l2out) {
    int b = blockIdx.x;
    int tid = threadIdx.x;               // 256
    int wave = tid >> 6, lane = tid & 63;
    __shared__ float uf[64], u1[64], u2[64];
    __shared__ float red[4];
    int u = user[b];
    if (tid < 64) {
        int rep = slot[u];
        float w0 = mw[0], w1 = mw[1], w2 = mw[2];
        float c0 = ubc[0 * BB + rep], c1 = ubc[1 * BB + rep], c2 = ubc[2 * BB + rep];
        float invT = 1.0f / (c0 * w0 + c1 * w1 + c2 * w2 + EPSF);
        float f = (c0 * w0 * invT) / (c0 + EPSF) * acc_neigh[(0 * BB + rep) * 64 + tid]
                + (c1 * w1 * invT) / (c1 + EPSF) * acc_neigh[(1 * BB + rep) * 64 + tid]
                + (c2 * w2 * invT) / (c2 + EPSF) * acc_neigh[(2 * BB + rep) * 64 + tid];
        uf[tid] = f;
        u1[tid] = user_emb[u * 64 + tid];
    }
    __syncthreads();
    if (tid < 64) {
        float o = 0.f;
#pragma unroll
        for (int k = 0; k < 64; k++) o += uf[k] * W[k * 64 + tid];
        u2[tid] = o;
    }
    __syncthreads();
    float l2part = 0.f;
    for (int k = wave; k < KK; k += 4) {
        int it = item[b * KK + k];
        float e1 = item_emb[it * 64 + lane], e2 = itf2[it * 64 + lane];
        float s = u1[lane] * e1 + u2[lane] * e2;
        float q = e1 * e1 + e2 * e2;
        for (int off = 32; off > 0; off >>= 1) {
            s += __shfl_xor(s, off);
            q += __shfl_xor(q, off);
        }
        if (lane == 0) {
            out[b * KK + k] = s + LAMBF * (score2[b * KK + k] * (1.0f / (float)RREL));
            l2part += q;
        }
    }
    float su = u1[lane] * u1[lane] + u2[lane] * u2[lane];
    for (int off = 32; off > 0; off >>= 1) su += __shfl_xor(su, off);
    if (wave == 0 && lane == 0) l2part += (float)KK * su;
    if (lane == 0) red[wave] = l2part;
    __syncthreads();
    if (tid == 0) atomicAdd(l2out, L2NORMF * (red[0] + red[1] + red[2] + red[3]));
}

extern "C" void kernel_launch(void* const* d_in, const int* in_sizes, int n_in,
                              void* d_out, int out_size, void* d_ws, size_t ws_size,
                              hipStream_t stream) {
    const int*   user       = (const int*)d_in[0];
    const int*   item       = (const int*)d_in[1];
    const int*   rel_rows   = (const int*)d_in[2];
    const int*   rel_cols   = (const int*)d_in[3];
    const int*   ig_rows    = (const int*)d_in[4];
    const int*   ig_cols    = (const int*)d_in[5];
    const float* ig_vals    = (const float*)d_in[6];
    const int*   train_rows = (const int*)d_in[7];
    const int*   train_cols = (const int*)d_in[8];
    const float* user_emb   = (const float*)d_in[9];
    const float* item_emb   = (const float*)d_in[10];
    const float* mw         = (const float*)d_in[11];
    const float* Wb         = (const float*)d_in[12];  // R x 128 x 128
    const float* Wp         = (const float*)d_in[13];  // R x 64 x 64
    const float* W          = (const float*)d_in[14];  // 64 x 64
    float* out = (float*)d_out;

    // ---- workspace layout (4-byte words; garr first for 8B alignment) ----
    float* ws = (float*)d_ws;
    size_t o = 0;
    int2*  garr       = (int2*)(ws + o); o += (size_t)IGTOT * 2;   // ig edges, 8B each
    int*   tcol       = (int*)(ws + o); o += NNZ_;                 // train edges
    int*   user_slot  = (int*)(ws + o); o += NUSERS;               // memset 0xFF
    int*   iflag      = (int*)(ws + o); o += NITEMS;               // memset 0
    int*   pcnt       = (int*)(ws + o); o += (size_t)NBLK * NBINS;
    int*   tot        = (int*)(ws + o); o += NBINS;
    int*   binbase    = (int*)(ws + o); o += NBINS + 1;
    int*   obase      = (int*)(ws + o); o += (size_t)NBLK * NBINS;
    float* item_prop2 = ws + o; o += (size_t)NITEMS * 64;          // reused as itf2 at the end
    // contiguous zero zone:
    float* acc_neigh  = ws + o; o += (size_t)RREL * BB * 64;
    float* acc_prop   = ws + o; o += (size_t)RREL * BB * 64;
    float* ubc        = ws + o; o += (size_t)RREL * BB;
    float* score2     = ws + o; o += (size_t)BB * KK;
    if (ws_size < o * sizeof(float)) return;   // undersized scratch: bail cleanly

    size_t zero_zone = (size_t)RREL * BB * 64 * 2 + RREL * BB + BB * KK;

    // phase 0: init
    hipMemsetAsync(user_slot, 0xFF, (size_t)NUSERS * 4, stream);          // = -1
    hipMemsetAsync(iflag, 0, (size_t)NITEMS * 4, stream);
    hipMemsetAsync(acc_neigh, 0, zero_zone * 4, stream);
    hipMemsetAsync(out + (out_size - 1), 0, 4, stream);                   // l2 slot
    scatter_maps<<<(BB * KK + 255) / 256, 256, 0, stream>>>(user, item, user_slot, iflag);

    // phase 1: atomic-free coarse bucketing (rank-based two-pass)
    pass1_count<<<NBLK, BTH, 0, stream>>>(ig_rows, train_cols, pcnt);
    scan_tot<<<(NBINS + 255) / 256, 256, 0, stream>>>(pcnt, tot);
    scan_bins<<<1, 1024, 0, stream>>>(tot, binbase);
    scan_obase<<<(NBINS + 255) / 256, 256, 0, stream>>>(pcnt, binbase, obase);
    pass2_scatter<<<NBLK, BTH, 0, stream>>>(ig_rows, ig_cols, ig_vals, train_rows, train_cols,
                                            obase, garr, tcol);

    // phase 2: per relation
    for (int i = 0; i < RREL; i++) {
        ig_bin_gather<<<NBIN_SEG, GTH, 0, stream>>>(item_emb, binbase, garr,
                                                    Wp + (size_t)i * 64 * 64, item_prop2, i);
        rel_scan<<<1024, 256, 0, stream>>>(rel_rows + (size_t)i * NNZ_, rel_cols + (size_t)i * NNZ_,
                                           user_slot, item_emb, item_prop2,
                                           acc_neigh + (size_t)i * BB * 64,
                                           acc_prop + (size_t)i * BB * 64, ubc + (size_t)i * BB);
        proj_score2<<<BB, 256, 0, stream>>>(user, user_slot, ubc + (size_t)i * BB,
                                            acc_neigh + (size_t)i * BB * 64,
                                            acc_prop + (size_t)i * BB * 64,
                                            Wb + (size_t)i * 128 * 128,
                                            item, item_emb, item_prop2, score2);
    }

    // phase 3: item_feature via bin gather, fused @W (itf2 reuses prop2 buffer)
    float* itf2 = item_prop2;
    train_bin_gather<<<NBIN_SEG, GTH, 0, stream>>>(user_emb, binbase, tcol, iflag, W, itf2);
    final_k<<<BB, 256, 0, stream>>>(user, item, user_slot, ubc, acc_neigh, mw, W,
                                    user_emb, item_emb, itf2, score2,
                                    out, out + (out_size - 1));
}

// Round 10
// 592.928 us; speedup vs baseline: 3.2396x; 1.0666x over previous
//
#include <hip/hip_runtime.h>

#define EPSF     1e-8f
#define LAMBF    0.5f
#define L2NORMF  1e-4f
#define NUSERS   100000
#define NITEMS   50000
#define EMB      64
#define RREL     3
#define NNZ_     1000000
#define IGNNZ    500000
#define BB       512
#define KK       100

#define IGTOT    (RREL * IGNNZ)               // 1.5M
#define TOTE     (IGTOT + NNZ_)               // 2.5M edges total
#define NBIN_SEG 782                          // ceil(50000/64)
#define NBINS    (4 * NBIN_SEG)               // 3128 coarse bins
#define NBLK     128                          // bucketing blocks
#define BTH      1024                         // bucketing block size
#define SLICE    ((TOTE + NBLK - 1) / NBLK)   // 19532
#define CAPE     2048                         // LDS stage capacity (avg bin: ig 640, train 1279)
#define GTH      512                          // gather block size (8 waves)

// user -> batch slot map + batch-item flags
__global__ void scatter_maps(const int* __restrict__ user, const int* __restrict__ item,
                             int* __restrict__ slot, int* __restrict__ iflag) {
    int i = blockIdx.x * blockDim.x + threadIdx.x;
    if (i < BB) slot[user[i]] = i;
    if (i < BB * KK) iflag[item[i]] = 1;
}

__device__ __forceinline__ int edge_bin(int i, const int* ig_rows, const int* train_cols) {
    if (i < IGTOT) return (i / IGNNZ) * NBIN_SEG + (ig_rows[i] >> 6);
    return 3 * NBIN_SEG + (train_cols[i - IGTOT] >> 6);
}

// pass 1: per-block LDS histogram over coarse bins -> pcnt[block][bin] (plain writes)
__global__ void pass1_count(const int* __restrict__ ig_rows, const int* __restrict__ train_cols,
                            int* __restrict__ pcnt) {
    __shared__ int h[NBINS];
    int b = blockIdx.x, t = threadIdx.x;
    for (int i = t; i < NBINS; i += BTH) h[i] = 0;
    __syncthreads();
    int s = b * SLICE, e = min(s + SLICE, TOTE);
    for (int i = s + t; i < e; i += BTH)
        atomicAdd(&h[edge_bin(i, ig_rows, train_cols)], 1);
    __syncthreads();
    for (int i = t; i < NBINS; i += BTH) pcnt[b * NBINS + i] = h[i];
}

// tot[bin] = sum over blocks (coalesced)
__global__ void scan_tot(const int* __restrict__ pcnt, int* __restrict__ tot) {
    int bin = blockIdx.x * blockDim.x + threadIdx.x;
    if (bin >= NBINS) return;
    int s = 0;
    for (int b = 0; b < NBLK; b++) s += pcnt[b * NBINS + bin];
    tot[bin] = s;
}

// exclusive scan of tot[NBINS] -> binbase (single block)
__global__ void scan_bins(const int* __restrict__ tot, int* __restrict__ binbase) {
    __shared__ int csum[1024];
    int t = threadIdx.x;
    int base = t * 4;
    int v0 = (base + 0 < NBINS) ? tot[base + 0] : 0;
    int v1 = (base + 1 < NBINS) ? tot[base + 1] : 0;
    int v2 = (base + 2 < NBINS) ? tot[base + 2] : 0;
    int v3 = (base + 3 < NBINS) ? tot[base + 3] : 0;
    int s = v0 + v1 + v2 + v3;
    csum[t] = s;
    __syncthreads();
    for (int d = 1; d < 1024; d <<= 1) {
        int x = (t >= d) ? csum[t - d] : 0;
        __syncthreads();
        csum[t] += x;
        __syncthreads();
    }
    int run = csum[t] - s;   // exclusive
    if (base + 0 < NBINS) { binbase[base + 0] = run; run += v0; }
    if (base + 1 < NBINS) { binbase[base + 1] = run; run += v1; }
    if (base + 2 < NBINS) { binbase[base + 2] = run; run += v2; }
    if (base + 3 < NBINS) { binbase[base + 3] = run; run += v3; }
    if (t == 0) binbase[NBINS] = TOTE;
}

// per-(block,bin) base offsets (coalesced across bin)
__global__ void scan_obase(const int* __restrict__ pcnt, const int* __restrict__ binbase,
                           int* __restrict__ obase) {
    int bin = blockIdx.x * blockDim.x + threadIdx.x;
    if (bin >= NBINS) return;
    int run = binbase[bin];
    for (int b = 0; b < NBLK; b++) {
        obase[b * NBINS + bin] = run;
        run += pcnt[b * NBINS + bin];
    }
}

// pass 2: place edges; rank via LDS counters seeded with obase (no global atomics)
__global__ void pass2_scatter(const int* __restrict__ ig_rows, const int* __restrict__ ig_cols,
                              const float* __restrict__ ig_vals, const int* __restrict__ train_rows,
                              const int* __restrict__ train_cols, const int* __restrict__ obase,
                              int2* __restrict__ garr, int* __restrict__ tcol) {
    __shared__ int pos[NBINS];
    int b = blockIdx.x, t = threadIdx.x;
    for (int i = t; i < NBINS; i += BTH) pos[i] = obase[b * NBINS + i];
    __syncthreads();
    int s = b * SLICE, e = min(s + SLICE, TOTE);
    for (int i = s + t; i < e; i += BTH) {
        if (i < IGTOT) {
            int dest = ig_rows[i];
            int bin = (i / IGNNZ) * NBIN_SEG + (dest >> 6);
            int slot = atomicAdd(&pos[bin], 1);
            garr[slot] = make_int2((ig_cols[i] << 6) | (dest & 63),
                                   __float_as_int(ig_vals[i]));
        } else {
            int e2 = i - IGTOT;
            int dest = train_cols[e2];
            int bin = 3 * NBIN_SEG + (dest >> 6);
            int slot = atomicAdd(&pos[bin], 1);
            tcol[slot - IGTOT] = (train_rows[e2] << 6) | (dest & 63);
        }
    }
}

// wave-0 exclusive scan over cnt[64] -> off, pos (replaces serial t==0 chain)
__device__ __forceinline__ void bin_scan(int t, int* cnt, int* off, int* pos) {
    if (t < 64) {
        int v = cnt[t];
        int inc = v;
#pragma unroll
        for (int d = 1; d < 64; d <<= 1) {
            int x = __shfl_up(inc, d);
            if (t >= d) inc += x;
        }
        off[t] = inc - v;
        pos[t] = inc - v;
        if (t == 63) off[64] = inc;
    }
}

// ig: block per 64-dest bin. LDS sort by dest, wave-per-dest masked 8-deep gather,
// normalize by deg -> prop2 (raw; @Wp applied by apply_w afterwards)
__global__ void ig_bin_gather(const float* __restrict__ item_emb, const int* __restrict__ binbase,
                              const int2* __restrict__ garr, float* __restrict__ prop2, int seg) {
    __shared__ int scol[CAPE];
    __shared__ float sval[CAPE];
    __shared__ int cnt[64], off[65], pos[64];
    int t = threadIdx.x, w = t >> 6, lane = t & 63;
    int bin = seg * NBIN_SEG + blockIdx.x;
    int bstart = binbase[bin], bend = binbase[bin + 1];
    int n = bend - bstart;
    int row0 = blockIdx.x * 64;
    if (n <= CAPE) {
        if (t < 64) cnt[t] = 0;
        __syncthreads();
        for (int i = t; i < n; i += GTH) atomicAdd(&cnt[garr[bstart + i].x & 63], 1);
        __syncthreads();
        bin_scan(t, cnt, off, pos);
        __syncthreads();
        for (int i = t; i < n; i += GTH) {
            int2 pv = garr[bstart + i];
            int sl = atomicAdd(&pos[pv.x & 63], 1);
            scol[sl] = pv.x >> 6;
            sval[sl] = __int_as_float(pv.y);
        }
        __syncthreads();
        for (int r = w; r < 64; r += 8) {
            int grow = row0 + r;
            if (grow >= NITEMS) break;
            int s = off[r], e = off[r + 1];
            float acc = 0.f, deg = 0.f;
            for (int k = s; k < e; k += 8) {
                int i0 = min(k + 0, e - 1), i1 = min(k + 1, e - 1);
                int i2 = min(k + 2, e - 1), i3 = min(k + 3, e - 1);
                int i4 = min(k + 4, e - 1), i5 = min(k + 5, e - 1);
                int i6 = min(k + 6, e - 1), i7 = min(k + 7, e - 1);
                int c0 = scol[i0], c1 = scol[i1], c2 = scol[i2], c3 = scol[i3];
                int c4 = scol[i4], c5 = scol[i5], c6 = scol[i6], c7 = scol[i7];
                float v0 = (k + 0 < e) ? sval[i0] : 0.f, v1 = (k + 1 < e) ? sval[i1] : 0.f;
                float v2 = (k + 2 < e) ? sval[i2] : 0.f, v3 = (k + 3 < e) ? sval[i3] : 0.f;
                float v4 = (k + 4 < e) ? sval[i4] : 0.f, v5 = (k + 5 < e) ? sval[i5] : 0.f;
                float v6 = (k + 6 < e) ? sval[i6] : 0.f, v7 = (k + 7 < e) ? sval[i7] : 0.f;
                float f0 = item_emb[c0 * 64 + lane], f1 = item_emb[c1 * 64 + lane];
                float f2 = item_emb[c2 * 64 + lane], f3 = item_emb[c3 * 64 + lane];
                float f4 = item_emb[c4 * 64 + lane], f5 = item_emb[c5 * 64 + lane];
                float f6 = item_emb[c6 * 64 + lane], f7 = item_emb[c7 * 64 + lane];
                acc += v0 * f0 + v1 * f1 + v2 * f2 + v3 * f3
                     + v4 * f4 + v5 * f5 + v6 * f6 + v7 * f7;
                deg += (v0 + v1 + v2 + v3) + (v4 + v5 + v6 + v7);
            }
            prop2[grow * 64 + lane] = acc / (deg + EPSF);
        }
    } else {
        // slow fallback (bin > CAPE; statistically never for this input)
        for (int r = w; r < 64; r += 8) {
            int grow = row0 + r;
            if (grow >= NITEMS) break;
            float acc = 0.f, deg = 0.f;
            for (int j0 = bstart; j0 < bend; j0 += 64) {
                int j = j0 + lane;
                int2 pv = (j < bend) ? garr[j] : make_int2(-1, 0);
                unsigned long long mask = __ballot(pv.x >= 0 && (pv.x & 63) == r);
                while (mask) {
                    int jj = __builtin_ctzll(mask); mask &= mask - 1;
                    int pj = __shfl(pv.x, jj);
                    float vj = __shfl(__int_as_float(pv.y), jj);
                    acc += vj * item_emb[(pj >> 6) * 64 + lane];
                    deg += vj;
                }
            }
            prop2[grow * 64 + lane] = acc / (deg + EPSF);
        }
    }
}

// train: block per 64-dest bin, iflag-gated, raw sum -> itf2 (@W applied by apply_w)
__global__ void train_bin_gather(const float* __restrict__ user_emb, const int* __restrict__ binbase,
                                 const int* __restrict__ tcol, const int* __restrict__ iflag,
                                 float* __restrict__ itf2) {
    __shared__ int scol[CAPE];
    __shared__ int cnt[64], off[65], pos[64];
    int t = threadIdx.x, w = t >> 6, lane = t & 63;
    int bin = 3 * NBIN_SEG + blockIdx.x;
    int bstart = binbase[bin] - IGTOT, bend = binbase[bin + 1] - IGTOT;
    int n = bend - bstart;
    int row0 = blockIdx.x * 64;
    if (n <= CAPE) {
        if (t < 64) cnt[t] = 0;
        __syncthreads();
        for (int i = t; i < n; i += GTH) atomicAdd(&cnt[tcol[bstart + i] & 63], 1);
        __syncthreads();
        bin_scan(t, cnt, off, pos);
        __syncthreads();
        for (int i = t; i < n; i += GTH) {
            int p = tcol[bstart + i];
            int sl = atomicAdd(&pos[p & 63], 1);
            scol[sl] = p >> 6;
        }
        __syncthreads();
        for (int r = w; r < 64; r += 8) {
            int grow = row0 + r;
            if (grow >= NITEMS) break;
            if (!iflag[grow]) continue;
            int s = off[r], e = off[r + 1];
            float acc = 0.f;
            for (int k = s; k < e; k += 8) {
                int i0 = min(k + 0, e - 1), i1 = min(k + 1, e - 1);
                int i2 = min(k + 2, e - 1), i3 = min(k + 3, e - 1);
                int i4 = min(k + 4, e - 1), i5 = min(k + 5, e - 1);
                int i6 = min(k + 6, e - 1), i7 = min(k + 7, e - 1);
                int c0 = scol[i0], c1 = scol[i1], c2 = scol[i2], c3 = scol[i3];
                int c4 = scol[i4], c5 = scol[i5], c6 = scol[i6], c7 = scol[i7];
                float m1 = (k + 1 < e) ? 1.f : 0.f, m2 = (k + 2 < e) ? 1.f : 0.f;
                float m3 = (k + 3 < e) ? 1.f : 0.f, m4 = (k + 4 < e) ? 1.f : 0.f;
                float m5 = (k + 5 < e) ? 1.f : 0.f, m6 = (k + 6 < e) ? 1.f : 0.f;
                float m7 = (k + 7 < e) ? 1.f : 0.f;
                float f0 = user_emb[c0 * 64 + lane], f1 = user_emb[c1 * 64 + lane];
                float f2 = user_emb[c2 * 64 + lane], f3 = user_emb[c3 * 64 + lane];
                float f4 = user_emb[c4 * 64 + lane], f5 = user_emb[c5 * 64 + lane];
                float f6 = user_emb[c6 * 64 + lane], f7 = user_emb[c7 * 64 + lane];
                acc += f0 + m1 * f1 + m2 * f2 + m3 * f3
                     + m4 * f4 + m5 * f5 + m6 * f6 + m7 * f7;
            }
            itf2[grow * 64 + lane] = acc;
        }
    } else {
        for (int r = w; r < 64; r += 8) {
            int grow = row0 + r;
            if (grow >= NITEMS) break;
            if (!iflag[grow]) continue;
            float acc = 0.f;
            for (int j0 = bstart; j0 < bend; j0 += 64) {
                int j = j0 + lane;
                int p = (j < bend) ? tcol[j] : -1;
                unsigned long long mask = __ballot(p >= 0 && (p & 63) == r);
                while (mask) {
                    int jj = __builtin_ctzll(mask); mask &= mask - 1;
                    int pj = __shfl(p, jj);
                    acc += user_emb[(pj >> 6) * 64 + lane];
                }
            }
            itf2[grow * 64 + lane] = acc;
        }
    }
}

// in-place A[row] = A[row] @ W, 4 rows/block staged in LDS (safe: block owns its rows).
// flag != null -> only flagged rows
__global__ void apply_w(float* __restrict__ A, const float* __restrict__ Wm,
                        const int* __restrict__ flag, int M) {
    __shared__ float sW[64 * 64];
    __shared__ float sA[4][64];
    int tid = threadIdx.x;               // 256
    for (int i = tid; i < 64 * 64; i += 256) sW[i] = Wm[i];
    int lr = tid >> 6, c = tid & 63;
    int row = blockIdx.x * 4 + lr;
    bool act = (row < M) && (!flag || flag[row]);
    if (act) sA[lr][c] = A[row * 64 + c];
    __syncthreads();
    if (act) {
        float o = 0.f;
#pragma unroll
        for (int k = 0; k < 64; k++) o += sA[lr][k] * sW[k * 64 + c];
        A[row * 64 + c] = o;
    }
}

__device__ __forceinline__ void rel_hit(int s, int c, int lane,
                                        const float* __restrict__ item_emb,
                                        const float* __restrict__ prop2,
                                        float* __restrict__ accN, float* __restrict__ accP,
                                        float* __restrict__ ubc) {
    unsigned long long mask = __ballot(s >= 0);
    while (mask) {
        int j = __builtin_ctzll(mask);
        mask &= mask - 1;
        int bs = __shfl(s, j);
        int bc = __shfl(c, j);
        atomicAdd(&accN[bs * EMB + lane], item_emb[bc * EMB + lane]);
        atomicAdd(&accP[bs * EMB + lane], prop2[bc * EMB + lane]);
        if (lane == 0) atomicAdd(&ubc[bs], 1.0f);
    }
}

// filtered relation scan (int4 per lane = 256 edges/wave/iter)
__global__ void rel_scan(const int* __restrict__ rows, const int* __restrict__ cols,
                         const int* __restrict__ slot, const float* __restrict__ item_emb,
                         const float* __restrict__ prop2,
                         float* __restrict__ accN, float* __restrict__ accP,
                         float* __restrict__ ubc) {
    int lane = threadIdx.x & 63;
    int gw = (blockIdx.x * blockDim.x + threadIdx.x) >> 6;
    int nw = (gridDim.x * blockDim.x) >> 6;
    for (int ch = gw; ch < NNZ_ / 256; ch += nw) {
        int base = ch * 256 + lane * 4;
        int4 r4 = *reinterpret_cast<const int4*>(rows + base);
        int4 c4 = *reinterpret_cast<const int4*>(cols + base);
        int s0 = slot[r4.x], s1 = slot[r4.y], s2 = slot[r4.z], s3 = slot[r4.w];
        rel_hit(s0, c4.x, lane, item_emb, prop2, accN, accP, ubc);
        rel_hit(s1, c4.y, lane, item_emb, prop2, accN, accP, ubc);
        rel_hit(s2, c4.z, lane, item_emb, prop2, accN, accP, ubc);
        rel_hit(s3, c4.w, lane, item_emb, prop2, accN, accP, ubc);
    }
}

// per batch row: proj = tmp_user_item_p[user[b]] @ Wb, then
// score2[b,k] += dot(proj, [item_emb[it] | prop2[it]])
__global__ void proj_score2(const int* __restrict__ user, const int* __restrict__ slot,
                            const float* __restrict__ ubc, const float* __restrict__ acc_neigh,
                            const float* __restrict__ acc_prop, const float* __restrict__ Wb,
                            const int* __restrict__ item, const float* __restrict__ item_emb,
                            const float* __restrict__ item_prop2, float* __restrict__ score2) {
    int b = blockIdx.x;
    int tid = threadIdx.x;               // 256
    __shared__ float tbuf[128];
    __shared__ float p[128];
    int rep = slot[user[b]];
    float inv = 1.0f / (ubc[rep] + EPSF);
    if (tid < 64)       tbuf[tid] = acc_neigh[rep * 64 + tid] * inv;
    else if (tid < 128) tbuf[tid] = acc_prop[rep * 64 + (tid - 64)] * inv;
    __syncthreads();
    if (tid < 128) {
        float o = 0.f;
#pragma unroll 8
        for (int k = 0; k < 128; k++) o += tbuf[k] * Wb[k * 128 + tid];
        p[tid] = o;
    }
    __syncthreads();
    int wave = tid >> 6, lane = tid & 63;
    for (int k = wave; k < KK; k += 4) {
        int it = item[b * KK + k];
        float s = p[lane] * item_emb[it * 64 + lane] + p[64 + lane] * item_prop2[it * 64 + lane];
        for (int off = 32; off > 0; off >>= 1) s += __shfl_xor(s, off);
        if (lane == 0) score2[b * KK + k] += s;
    }
}

// final: ufeat + @W in-block, then score1 + LAMB*score2/R + l2
__global__ void final_k(const int* __restrict__ user, const int* __restrict__ item,
                        const int* __restrict__ slot, const float* __restrict__ ubc,
                        const float* __restrict__ acc_neigh, const float* __restrict__ mw,
                        const float* __restrict__ W, const float* __restrict__ user_emb,
                        const float* __restrict__ item_emb, const float* __restrict__ itf2,
                        const float* __restrict__ score2, float* __restrict__ out,
                        float* __restrict__ l2out) {
    int b = blockIdx.x;
    int tid = threadIdx.x;               // 256
    int wave = tid >> 6, lane = tid & 63;
    __shared__ float uf[64], u1[64], u2[64];
    __shared__ float red[4];
    int u = user[b];
    if (tid < 64) {
        int rep = slot[u];
        float w0 = mw[0], w1 = mw[1], w2 = mw[2];
        float c0 = ubc[0 * BB + rep], c1 = ubc[1 * BB + rep], c2 = ubc[2 * BB + rep];
        float invT = 1.0f / (c0 * w0 + c1 * w1 + c2 * w2 + EPSF);
        float f = (c0 * w0 * invT) / (c0 + EPSF) * acc_neigh[(0 * BB + rep) * 64 + tid]
                + (c1 * w1 * invT) / (c1 + EPSF) * acc_neigh[(1 * BB + rep) * 64 + tid]
                + (c2 * w2 * invT) / (c2 + EPSF) * acc_neigh[(2 * BB + rep) * 64 + tid];
        uf[tid] = f;
        u1[tid] = user_emb[u * 64 + tid];
    }
    __syncthreads();
    if (tid < 64) {
        float o = 0.f;
#pragma unroll
        for (int k = 0; k < 64; k++) o += uf[k] * W[k * 64 + tid];
        u2[tid] = o;
    }
    __syncthreads();
    float l2part = 0.f;
    for (int k = wave; k < KK; k += 4) {
        int it = item[b * KK + k];
        float e1 = item_emb[it * 64 + lane], e2 = itf2[it * 64 + lane];
        float s = u1[lane] * e1 + u2[lane] * e2;
        float q = e1 * e1 + e2 * e2;
        for (int off = 32; off > 0; off >>= 1) {
            s += __shfl_xor(s, off);
            q += __shfl_xor(q, off);
        }
        if (lane == 0) {
            out[b * KK + k] = s + LAMBF * (score2[b * KK + k] * (1.0f / (float)RREL));
            l2part += q;
        }
    }
    float su = u1[lane] * u1[lane] + u2[lane] * u2[lane];
    for (int off = 32; off > 0; off >>= 1) su += __shfl_xor(su, off);
    if (wave == 0 && lane == 0) l2part += (float)KK * su;
    if (lane == 0) red[wave] = l2part;
    __syncthreads();
    if (tid == 0) atomicAdd(l2out, L2NORMF * (red[0] + red[1] + red[2] + red[3]));
}

extern "C" void kernel_launch(void* const* d_in, const int* in_sizes, int n_in,
                              void* d_out, int out_size, void* d_ws, size_t ws_size,
                              hipStream_t stream) {
    const int*   user       = (const int*)d_in[0];
    const int*   item       = (const int*)d_in[1];
    const int*   rel_rows   = (const int*)d_in[2];
    const int*   rel_cols   = (const int*)d_in[3];
    const int*   ig_rows    = (const int*)d_in[4];
    const int*   ig_cols    = (const int*)d_in[5];
    const float* ig_vals    = (const float*)d_in[6];
    const int*   train_rows = (const int*)d_in[7];
    const int*   train_cols = (const int*)d_in[8];
    const float* user_emb   = (const float*)d_in[9];
    const float* item_emb   = (const float*)d_in[10];
    const float* mw         = (const float*)d_in[11];
    const float* Wb         = (const float*)d_in[12];  // R x 128 x 128
    const float* Wp         = (const float*)d_in[13];  // R x 64 x 64
    const float* W          = (const float*)d_in[14];  // 64 x 64
    float* out = (float*)d_out;

    // ---- workspace layout (4-byte words; garr first for 8B alignment) ----
    float* ws = (float*)d_ws;
    size_t o = 0;
    int2*  garr       = (int2*)(ws + o); o += (size_t)IGTOT * 2;   // ig edges, 8B each
    int*   tcol       = (int*)(ws + o); o += NNZ_;                 // train edges
    int*   user_slot  = (int*)(ws + o); o += NUSERS;               // memset 0xFF
    int*   iflag      = (int*)(ws + o); o += NITEMS;               // memset 0
    int*   pcnt       = (int*)(ws + o); o += (size_t)NBLK * NBINS;
    int*   tot        = (int*)(ws + o); o += NBINS;
    int*   binbase    = (int*)(ws + o); o += NBINS + 1;
    int*   obase      = (int*)(ws + o); o += (size_t)NBLK * NBINS;
    float* item_prop2 = ws + o; o += (size_t)NITEMS * 64;          // reused as itf2 at the end
    // contiguous zero zone:
    float* acc_neigh  = ws + o; o += (size_t)RREL * BB * 64;
    float* acc_prop   = ws + o; o += (size_t)RREL * BB * 64;
    float* ubc        = ws + o; o += (size_t)RREL * BB;
    float* score2     = ws + o; o += (size_t)BB * KK;
    if (ws_size < o * sizeof(float)) return;   // undersized scratch: bail cleanly

    size_t zero_zone = (size_t)RREL * BB * 64 * 2 + RREL * BB + BB * KK;

    // phase 0: init
    hipMemsetAsync(user_slot, 0xFF, (size_t)NUSERS * 4, stream);          // = -1
    hipMemsetAsync(iflag, 0, (size_t)NITEMS * 4, stream);
    hipMemsetAsync(acc_neigh, 0, zero_zone * 4, stream);
    hipMemsetAsync(out + (out_size - 1), 0, 4, stream);                   // l2 slot
    scatter_maps<<<(BB * KK + 255) / 256, 256, 0, stream>>>(user, item, user_slot, iflag);

    // phase 1: atomic-free coarse bucketing (rank-based two-pass)
    pass1_count<<<NBLK, BTH, 0, stream>>>(ig_rows, train_cols, pcnt);
    scan_tot<<<(NBINS + 255) / 256, 256, 0, stream>>>(pcnt, tot);
    scan_bins<<<1, 1024, 0, stream>>>(tot, binbase);
    scan_obase<<<(NBINS + 255) / 256, 256, 0, stream>>>(pcnt, binbase, obase);
    pass2_scatter<<<NBLK, BTH, 0, stream>>>(ig_rows, ig_cols, ig_vals, train_rows, train_cols,
                                            obase, garr, tcol);

    // phase 2: per relation (gather raw -> apply Wp in-place -> rel scan -> score2)
    for (int i = 0; i < RREL; i++) {
        ig_bin_gather<<<NBIN_SEG, GTH, 0, stream>>>(item_emb, binbase, garr, item_prop2, i);
        apply_w<<<(NITEMS + 3) / 4, 256, 0, stream>>>(item_prop2, Wp + (size_t)i * 64 * 64,
                                                      nullptr, NITEMS);
        rel_scan<<<1024, 256, 0, stream>>>(rel_rows + (size_t)i * NNZ_, rel_cols + (size_t)i * NNZ_,
                                           user_slot, item_emb, item_prop2,
                                           acc_neigh + (size_t)i * BB * 64,
                                           acc_prop + (size_t)i * BB * 64, ubc + (size_t)i * BB);
        proj_score2<<<BB, 256, 0, stream>>>(user, user_slot, ubc + (size_t)i * BB,
                                            acc_neigh + (size_t)i * BB * 64,
                                            acc_prop + (size_t)i * BB * 64,
                                            Wb + (size_t)i * 128 * 128,
                                            item, item_emb, item_prop2, score2);
    }

    // phase 3: item_feature raw gather -> apply W in-place (flagged rows only)
    float* itf2 = item_prop2;
    train_bin_gather<<<NBIN_SEG, GTH, 0, stream>>>(user_emb, binbase, tcol, iflag, itf2);
    apply_w<<<(NITEMS + 3) / 4, 256, 0, stream>>>(itf2, W, iflag, NITEMS);
    final_k<<<BB, 256, 0, stream>>>(user, item, user_slot, ubc, acc_neigh, mw, W,
                                    user_emb, item_emb, itf2, score2,
                                    out, out + (out_size - 1));
}

// Round 12
// 516.146 us; speedup vs baseline: 3.7216x; 1.1488x over previous
//
#include <hip/hip_runtime.h>

#define EPSF     1e-8f
#define LAMBF    0.5f
#define L2NORMF  1e-4f
#define NUSERS   100000
#define NITEMS   50000
#define EMB      64
#define RREL     3
#define NNZ_     1000000
#define IGNNZ    500000
#define BB       512
#define KK       100

#define IGTOT    (RREL * IGNNZ)               // 1.5M
#define TOTE     (IGTOT + NNZ_)               // 2.5M edges total
#define NBIN_SEG 782                          // ceil(50000/64)
#define NBINS    (4 * NBIN_SEG)               // 3128 coarse bins
#define NBLK     64                           // bucketing blocks (fewer -> longer runs)
#define BTH      1024                         // bucketing block size
#define SLICE    ((TOTE + NBLK - 1) / NBLK)
#define CAPE     2048                         // LDS stage capacity
#define GTH      512                          // gather block size (8 waves)
#define BPM      ((NITEMS + 3) / 4)           // apply blocks per matrix (12500)
#define CHUNKS   ((NNZ_ + 255) / 256)         // rel chunks incl. tail (3907)

// user -> batch slot map + batch-item flags
__global__ void scatter_maps(const int* __restrict__ user, const int* __restrict__ item,
                             int* __restrict__ slot, int* __restrict__ iflag) {
    int i = blockIdx.x * blockDim.x + threadIdx.x;
    if (i < BB) slot[user[i]] = i;
    if (i < BB * KK) iflag[item[i]] = 1;
}

__device__ __forceinline__ int edge_bin(int i, const int* ig_rows, const int* train_cols) {
    if (i < IGTOT) return (i / IGNNZ) * NBIN_SEG + (ig_rows[i] >> 6);
    return 3 * NBIN_SEG + (train_cols[i - IGTOT] >> 6);
}

__global__ void pass1_count(const int* __restrict__ ig_rows, const int* __restrict__ train_cols,
                            int* __restrict__ pcnt) {
    __shared__ int h[NBINS];
    int b = blockIdx.x, t = threadIdx.x;
    for (int i = t; i < NBINS; i += BTH) h[i] = 0;
    __syncthreads();
    int s = b * SLICE, e = min(s + SLICE, TOTE);
    for (int i = s + t; i < e; i += BTH)
        atomicAdd(&h[edge_bin(i, ig_rows, train_cols)], 1);
    __syncthreads();
    for (int i = t; i < NBINS; i += BTH) pcnt[b * NBINS + i] = h[i];
}

__global__ void scan_tot(const int* __restrict__ pcnt, int* __restrict__ tot) {
    int bin = blockIdx.x * blockDim.x + threadIdx.x;
    if (bin >= NBINS) return;
    int s = 0;
    for (int b = 0; b < NBLK; b++) s += pcnt[b * NBINS + bin];
    tot[bin] = s;
}

__global__ void scan_bins(const int* __restrict__ tot, int* __restrict__ binbase) {
    __shared__ int csum[1024];
    int t = threadIdx.x;
    int base = t * 4;
    int v0 = (base + 0 < NBINS) ? tot[base + 0] : 0;
    int v1 = (base + 1 < NBINS) ? tot[base + 1] : 0;
    int v2 = (base + 2 < NBINS) ? tot[base + 2] : 0;
    int v3 = (base + 3 < NBINS) ? tot[base + 3] : 0;
    int s = v0 + v1 + v2 + v3;
    csum[t] = s;
    __syncthreads();
    for (int d = 1; d < 1024; d <<= 1) {
        int x = (t >= d) ? csum[t - d] : 0;
        __syncthreads();
        csum[t] += x;
        __syncthreads();
    }
    int run = csum[t] - s;
    if (base + 0 < NBINS) { binbase[base + 0] = run; run += v0; }
    if (base + 1 < NBINS) { binbase[base + 1] = run; run += v1; }
    if (base + 2 < NBINS) { binbase[base + 2] = run; run += v2; }
    if (base + 3 < NBINS) { binbase[base + 3] = run; run += v3; }
    if (t == 0) binbase[NBINS] = TOTE;
}

__global__ void scan_obase(const int* __restrict__ pcnt, const int* __restrict__ binbase,
                           int* __restrict__ obase) {
    int bin = blockIdx.x * blockDim.x + threadIdx.x;
    if (bin >= NBINS) return;
    int run = binbase[bin];
    for (int b = 0; b < NBLK; b++) {
        obase[b * NBINS + bin] = run;
        run += pcnt[b * NBINS + bin];
    }
}

__global__ void pass2_scatter(const int* __restrict__ ig_rows, const int* __restrict__ ig_cols,
                              const float* __restrict__ ig_vals, const int* __restrict__ train_rows,
                              const int* __restrict__ train_cols, const int* __restrict__ obase,
                              int2* __restrict__ garr, int* __restrict__ tcol) {
    __shared__ int pos[NBINS];
    int b = blockIdx.x, t = threadIdx.x;
    for (int i = t; i < NBINS; i += BTH) pos[i] = obase[b * NBINS + i];
    __syncthreads();
    int s = b * SLICE, e = min(s + SLICE, TOTE);
    for (int i = s + t; i < e; i += BTH) {
        if (i < IGTOT) {
            int dest = ig_rows[i];
            int bin = (i / IGNNZ) * NBIN_SEG + (dest >> 6);
            int slot = atomicAdd(&pos[bin], 1);
            garr[slot] = make_int2((ig_cols[i] << 6) | (dest & 63),
                                   __float_as_int(ig_vals[i]));
        } else {
            int e2 = i - IGTOT;
            int dest = train_cols[e2];
            int bin = 3 * NBIN_SEG + (dest >> 6);
            int slot = atomicAdd(&pos[bin], 1);
            tcol[slot - IGTOT] = (train_rows[e2] << 6) | (dest & 63);
        }
    }
}

// wave-0 exclusive scan over cnt[64] -> off, pos
__device__ __forceinline__ void bin_scan(int t, int* cnt, int* off, int* pos) {
    if (t < 64) {
        int v = cnt[t];
        int inc = v;
#pragma unroll
        for (int d = 1; d < 64; d <<= 1) {
            int x = __shfl_up(inc, d);
            if (t >= d) inc += x;
        }
        off[t] = inc - v;
        pos[t] = inc - v;
        if (t == 63) off[64] = inc;
    }
}

// unified gather: seg = seg_base + blockIdx.x/NBIN_SEG; segs 0..2 = ig (raw avg ->
// prop2 + (seg-seg_base)*pstride), seg 3 = train (raw sum -> itf2, iflag-gated)
__global__ void gather_all(const float* __restrict__ item_emb, const float* __restrict__ user_emb,
                           const int* __restrict__ binbase, const int2* __restrict__ garr,
                           const int* __restrict__ tcol, const int* __restrict__ iflag,
                           float* __restrict__ prop2, size_t pstride, float* __restrict__ itf2,
                           int seg_base) {
    __shared__ int scol[CAPE];
    __shared__ float sval[CAPE];
    __shared__ int cnt[64], off[65], pos[64];
    int t = threadIdx.x, w = t >> 6, lane = t & 63;
    int seg = seg_base + blockIdx.x / NBIN_SEG;
    int lbin = blockIdx.x % NBIN_SEG;
    int bin = seg * NBIN_SEG + lbin;
    int row0 = lbin * 64;
    if (seg < 3) {
        float* outp = prop2 + (size_t)(seg - seg_base) * pstride;
        int bstart = binbase[bin], bend = binbase[bin + 1];
        int n = bend - bstart;
        if (n <= CAPE) {
            if (t < 64) cnt[t] = 0;
            __syncthreads();
            for (int i = t; i < n; i += GTH) atomicAdd(&cnt[garr[bstart + i].x & 63], 1);
            __syncthreads();
            bin_scan(t, cnt, off, pos);
            __syncthreads();
            for (int i = t; i < n; i += GTH) {
                int2 pv = garr[bstart + i];
                int sl = atomicAdd(&pos[pv.x & 63], 1);
                scol[sl] = pv.x >> 6;
                sval[sl] = __int_as_float(pv.y);
            }
            __syncthreads();
            for (int r = w; r < 64; r += 8) {
                int grow = row0 + r;
                if (grow >= NITEMS) break;
                int s = off[r], e = off[r + 1];
                float acc = 0.f, deg = 0.f;
                for (int k = s; k < e; k += 8) {
                    int i0 = min(k + 0, e - 1), i1 = min(k + 1, e - 1);
                    int i2 = min(k + 2, e - 1), i3 = min(k + 3, e - 1);
                    int i4 = min(k + 4, e - 1), i5 = min(k + 5, e - 1);
                    int i6 = min(k + 6, e - 1), i7 = min(k + 7, e - 1);
                    int c0 = scol[i0], c1 = scol[i1], c2 = scol[i2], c3 = scol[i3];
                    int c4 = scol[i4], c5 = scol[i5], c6 = scol[i6], c7 = scol[i7];
                    float v0 = (k + 0 < e) ? sval[i0] : 0.f, v1 = (k + 1 < e) ? sval[i1] : 0.f;
                    float v2 = (k + 2 < e) ? sval[i2] : 0.f, v3 = (k + 3 < e) ? sval[i3] : 0.f;
                    float v4 = (k + 4 < e) ? sval[i4] : 0.f, v5 = (k + 5 < e) ? sval[i5] : 0.f;
                    float v6 = (k + 6 < e) ? sval[i6] : 0.f, v7 = (k + 7 < e) ? sval[i7] : 0.f;
                    float f0 = item_emb[c0 * 64 + lane], f1 = item_emb[c1 * 64 + lane];
                    float f2 = item_emb[c2 * 64 + lane], f3 = item_emb[c3 * 64 + lane];
                    float f4 = item_emb[c4 * 64 + lane], f5 = item_emb[c5 * 64 + lane];
                    float f6 = item_emb[c6 * 64 + lane], f7 = item_emb[c7 * 64 + lane];
                    acc += v0 * f0 + v1 * f1 + v2 * f2 + v3 * f3
                         + v4 * f4 + v5 * f5 + v6 * f6 + v7 * f7;
                    deg += (v0 + v1 + v2 + v3) + (v4 + v5 + v6 + v7);
                }
                outp[grow * 64 + lane] = acc / (deg + EPSF);
            }
        } else {
            for (int r = w; r < 64; r += 8) {
                int grow = row0 + r;
                if (grow >= NITEMS) break;
                float acc = 0.f, deg = 0.f;
                for (int j0 = bstart; j0 < bend; j0 += 64) {
                    int j = j0 + lane;
                    int2 pv = (j < bend) ? garr[j] : make_int2(-1, 0);
                    unsigned long long mask = __ballot(pv.x >= 0 && (pv.x & 63) == r);
                    while (mask) {
                        int jj = __builtin_ctzll(mask); mask &= mask - 1;
                        int pj = __shfl(pv.x, jj);
                        float vj = __shfl(__int_as_float(pv.y), jj);
                        acc += vj * item_emb[(pj >> 6) * 64 + lane];
                        deg += vj;
                    }
                }
                outp[grow * 64 + lane] = acc / (deg + EPSF);
            }
        }
    } else {
        int bstart = binbase[bin] - IGTOT, bend = binbase[bin + 1] - IGTOT;
        int n = bend - bstart;
        if (n <= CAPE) {
            if (t < 64) cnt[t] = 0;
            __syncthreads();
            for (int i = t; i < n; i += GTH) atomicAdd(&cnt[tcol[bstart + i] & 63], 1);
            __syncthreads();
            bin_scan(t, cnt, off, pos);
            __syncthreads();
            for (int i = t; i < n; i += GTH) {
                int p = tcol[bstart + i];
                int sl = atomicAdd(&pos[p & 63], 1);
                scol[sl] = p >> 6;
            }
            __syncthreads();
            for (int r = w; r < 64; r += 8) {
                int grow = row0 + r;
                if (grow >= NITEMS) break;
                if (!iflag[grow]) continue;
                int s = off[r], e = off[r + 1];
                float acc = 0.f;
                for (int k = s; k < e; k += 8) {
                    int i0 = min(k + 0, e - 1), i1 = min(k + 1, e - 1);
                    int i2 = min(k + 2, e - 1), i3 = min(k + 3, e - 1);
                    int i4 = min(k + 4, e - 1), i5 = min(k + 5, e - 1);
                    int i6 = min(k + 6, e - 1), i7 = min(k + 7, e - 1);
                    int c0 = scol[i0], c1 = scol[i1], c2 = scol[i2], c3 = scol[i3];
                    int c4 = scol[i4], c5 = scol[i5], c6 = scol[i6], c7 = scol[i7];
                    float m1 = (k + 1 < e) ? 1.f : 0.f, m2 = (k + 2 < e) ? 1.f : 0.f;
                    float m3 = (k + 3 < e) ? 1.f : 0.f, m4 = (k + 4 < e) ? 1.f : 0.f;
                    float m5 = (k + 5 < e) ? 1.f : 0.f, m6 = (k + 6 < e) ? 1.f : 0.f;
                    float m7 = (k + 7 < e) ? 1.f : 0.f;
                    float f0 = user_emb[c0 * 64 + lane], f1 = user_emb[c1 * 64 + lane];
                    float f2 = user_emb[c2 * 64 + lane], f3 = user_emb[c3 * 64 + lane];
                    float f4 = user_emb[c4 * 64 + lane], f5 = user_emb[c5 * 64 + lane];
                    float f6 = user_emb[c6 * 64 + lane], f7 = user_emb[c7 * 64 + lane];
                    acc += f0 + m1 * f1 + m2 * f2 + m3 * f3
                         + m4 * f4 + m5 * f5 + m6 * f6 + m7 * f7;
                }
                itf2[grow * 64 + lane] = acc;
            }
        } else {
            for (int r = w; r < 64; r += 8) {
                int grow = row0 + r;
                if (grow >= NITEMS) break;
                if (!iflag[grow]) continue;
                float acc = 0.f;
                for (int j0 = bstart; j0 < bend; j0 += 64) {
                    int j = j0 + lane;
                    int p = (j < bend) ? tcol[j] : -1;
                    unsigned long long mask = __ballot(p >= 0 && (p & 63) == r);
                    while (mask) {
                        int jj = __builtin_ctzll(mask); mask &= mask - 1;
                        int pj = __shfl(p, jj);
                        acc += user_emb[(pj >> 6) * 64 + lane];
                    }
                }
                itf2[grow * 64 + lane] = acc;
            }
        }
    }
}

// unified in-place @W: m = m_base + blockIdx.x/BPM; m<3 -> prop2[m]@Wp[m]; m=3 -> itf2@W gated
__global__ void apply_all(float* __restrict__ prop2, size_t pstride, float* __restrict__ itf2,
                          const float* __restrict__ Wp, const float* __restrict__ W,
                          const int* __restrict__ iflag, int m_base) {
    __shared__ float sW[64 * 64];
    __shared__ float sA[4][64];
    int tid = threadIdx.x;               // 256
    int m = m_base + blockIdx.x / BPM;
    int blk = blockIdx.x % BPM;
    float* A; const float* Wm; const int* flag;
    if (m < 3) { A = prop2 + (size_t)(m - m_base) * pstride; Wm = Wp + (size_t)m * 4096; flag = nullptr; }
    else       { A = itf2; Wm = W; flag = iflag; }
    for (int i = tid; i < 64 * 64; i += 256) sW[i] = Wm[i];
    int lr = tid >> 6, c = tid & 63;
    int row = blk * 4 + lr;
    bool act = (row < NITEMS) && (!flag || flag[row]);
    if (act) sA[lr][c] = A[row * 64 + c];
    __syncthreads();
    if (act) {
        float o = 0.f;
#pragma unroll
        for (int k = 0; k < 64; k++) o += sA[lr][k] * sW[k * 64 + c];
        A[row * 64 + c] = o;
    }
}

__device__ __forceinline__ void rel_hit(int s, int c, int lane,
                                        const float* __restrict__ item_emb,
                                        const float* __restrict__ prop2,
                                        float* __restrict__ accN, float* __restrict__ accP,
                                        float* __restrict__ ubc) {
    unsigned long long mask = __ballot(s >= 0);
    while (mask) {
        int j = __builtin_ctzll(mask);
        mask &= mask - 1;
        int bs = __shfl(s, j);
        int bc = __shfl(c, j);
        atomicAdd(&accN[bs * EMB + lane], item_emb[bc * EMB + lane]);
        atomicAdd(&accP[bs * EMB + lane], prop2[bc * EMB + lane]);
        if (lane == 0) atomicAdd(&ubc[bs], 1.0f);
    }
}

// fused relation scan over nrel relations (incl. tail chunk fix)
__global__ void rel_scan_all(const int* __restrict__ rel_rows, const int* __restrict__ rel_cols,
                             const int* __restrict__ slot, const float* __restrict__ item_emb,
                             const float* __restrict__ prop2, size_t pstride,
                             float* __restrict__ accN, float* __restrict__ accP,
                             float* __restrict__ ubc, int rel_base, int nrel) {
    int lane = threadIdx.x & 63;
    int gw = (blockIdx.x * blockDim.x + threadIdx.x) >> 6;
    int nw = (gridDim.x * blockDim.x) >> 6;
    for (int ch = gw; ch < nrel * CHUNKS; ch += nw) {
        int rel = rel_base + ch / CHUNKS;
        int lch = ch % CHUNKS;
        const int* rows = rel_rows + (size_t)rel * NNZ_;
        const int* cols = rel_cols + (size_t)rel * NNZ_;
        const float* pr = prop2 + (size_t)(rel - rel_base) * pstride;
        float* aN = accN + (size_t)rel * BB * 64;
        float* aP = accP + (size_t)rel * BB * 64;
        float* ub = ubc + (size_t)rel * BB;
        int base = lch * 256 + lane * 4;
        if (base >= NNZ_) continue;           // tail guard (NNZ_ % 4 == 0)
        int4 r4 = *reinterpret_cast<const int4*>(rows + base);
        int4 c4 = *reinterpret_cast<const int4*>(cols + base);
        int s0 = slot[r4.x], s1 = slot[r4.y], s2 = slot[r4.z], s3 = slot[r4.w];
        rel_hit(s0, c4.x, lane, item_emb, pr, aN, aP, ub);
        rel_hit(s1, c4.y, lane, item_emb, pr, aN, aP, ub);
        rel_hit(s2, c4.z, lane, item_emb, pr, aN, aP, ub);
        rel_hit(s3, c4.w, lane, item_emb, pr, aN, aP, ub);
    }
}

// fused proj+score2 over nrel relations (score2 accumulated atomically)
__global__ void proj_all(const int* __restrict__ user, const int* __restrict__ slot,
                         const float* __restrict__ ubc_all, const float* __restrict__ accN_all,
                         const float* __restrict__ accP_all, const float* __restrict__ Wb,
                         const int* __restrict__ item, const float* __restrict__ item_emb,
                         const float* __restrict__ prop2, size_t pstride,
                         float* __restrict__ score2, int rel_base) {
    int rel = rel_base + blockIdx.x / BB;
    int b = blockIdx.x % BB;
    int tid = threadIdx.x;               // 256
    __shared__ float tbuf[128];
    __shared__ float p[128];
    const float* ubc = ubc_all + (size_t)rel * BB;
    const float* accN = accN_all + (size_t)rel * BB * 64;
    const float* accP = accP_all + (size_t)rel * BB * 64;
    const float* Wbr = Wb + (size_t)rel * 128 * 128;
    const float* pr = prop2 + (size_t)(rel - rel_base) * pstride;
    int rep = slot[user[b]];
    float inv = 1.0f / (ubc[rep] + EPSF);
    if (tid < 64)       tbuf[tid] = accN[rep * 64 + tid] * inv;
    else if (tid < 128) tbuf[tid] = accP[rep * 64 + (tid - 64)] * inv;
    __syncthreads();
    if (tid < 128) {
        float o = 0.f;
#pragma unroll 8
        for (int k = 0; k < 128; k++) o += tbuf[k] * Wbr[k * 128 + tid];
        p[tid] = o;
    }
    __syncthreads();
    int wave = tid >> 6, lane = tid & 63;
    for (int k = wave; k < KK; k += 4) {
        int it = item[b * KK + k];
        float s = p[lane] * item_emb[it * 64 + lane] + p[64 + lane] * pr[it * 64 + lane];
        for (int off = 32; off > 0; off >>= 1) s += __shfl_xor(s, off);
        if (lane == 0) atomicAdd(&score2[b * KK + k], s);
    }
}

// final: ufeat + @W in-block, then score1 + LAMB*score2/R + l2
__global__ void final_k(const int* __restrict__ user, const int* __restrict__ item,
                        const int* __restrict__ slot, const float* __restrict__ ubc,
                        const float* __restrict__ acc_neigh, const float* __restrict__ mw,
                        const float* __restrict__ W, const float* __restrict__ user_emb,
                        const float* __restrict__ item_emb, const float* __restrict__ itf2,
                        const float* __restrict__ score2, float* __restrict__ out,
                        float* __restrict__ l2out) {
    int b = blockIdx.x;
    int tid = threadIdx.x;               // 256
    int wave = tid >> 6, lane = tid & 63;
    __shared__ float uf[64], u1[64], u2[64];
    __shared__ float red[4];
    int u = user[b];
    if (tid < 64) {
        int rep = slot[u];
        float w0 = mw[0], w1 = mw[1], w2 = mw[2];
        float c0 = ubc[0 * BB + rep], c1 = ubc[1 * BB + rep], c2 = ubc[2 * BB + rep];
        float invT = 1.0f / (c0 * w0 + c1 * w1 + c2 * w2 + EPSF);
        float f = (c0 * w0 * invT) / (c0 + EPSF) * acc_neigh[(0 * BB + rep) * 64 + tid]
                + (c1 * w1 * invT) / (c1 + EPSF) * acc_neigh[(1 * BB + rep) * 64 + tid]
                + (c2 * w2 * invT) / (c2 + EPSF) * acc_neigh[(2 * BB + rep) * 64 + tid];
        uf[tid] = f;
        u1[tid] = user_emb[u * 64 + tid];
    }
    __syncthreads();
    if (tid < 64) {
        float o = 0.f;
#pragma unroll
        for (int k = 0; k < 64; k++) o += uf[k] * W[k * 64 + tid];
        u2[tid] = o;
    }
    __syncthreads();
    float l2part = 0.f;
    for (int k = wave; k < KK; k += 4) {
        int it = item[b * KK + k];
        float e1 = item_emb[it * 64 + lane], e2 = itf2[it * 64 + lane];
        float s = u1[lane] * e1 + u2[lane] * e2;
        float q = e1 * e1 + e2 * e2;
        for (int off = 32; off > 0; off >>= 1) {
            s += __shfl_xor(s, off);
            q += __shfl_xor(q, off);
        }
        if (lane == 0) {
            out[b * KK + k] = s + LAMBF * (score2[b * KK + k] * (1.0f / (float)RREL));
            l2part += q;
        }
    }
    float su = u1[lane] * u1[lane] + u2[lane] * u2[lane];
    for (int off = 32; off > 0; off >>= 1) su += __shfl_xor(su, off);
    if (wave == 0 && lane == 0) l2part += (float)KK * su;
    if (lane == 0) red[wave] = l2part;
    __syncthreads();
    if (tid == 0) atomicAdd(l2out, L2NORMF * (red[0] + red[1] + red[2] + red[3]));
}

extern "C" void kernel_launch(void* const* d_in, const int* in_sizes, int n_in,
                              void* d_out, int out_size, void* d_ws, size_t ws_size,
                              hipStream_t stream) {
    const int*   user       = (const int*)d_in[0];
    const int*   item       = (const int*)d_in[1];
    const int*   rel_rows   = (const int*)d_in[2];
    const int*   rel_cols   = (const int*)d_in[3];
    const int*   ig_rows    = (const int*)d_in[4];
    const int*   ig_cols    = (const int*)d_in[5];
    const float* ig_vals    = (const float*)d_in[6];
    const int*   train_rows = (const int*)d_in[7];
    const int*   train_cols = (const int*)d_in[8];
    const float* user_emb   = (const float*)d_in[9];
    const float* item_emb   = (const float*)d_in[10];
    const float* mw         = (const float*)d_in[11];
    const float* Wb         = (const float*)d_in[12];  // R x 128 x 128
    const float* Wp         = (const float*)d_in[13];  // R x 64 x 64
    const float* W          = (const float*)d_in[14];  // 64 x 64
    float* out = (float*)d_out;

    const size_t PM = (size_t)NITEMS * 64;

    // common prefix layout (words)
    float* ws = (float*)d_ws;
    size_t o = 0;
    int2*  garr       = (int2*)(ws + o); o += (size_t)IGTOT * 2;
    int*   tcol       = (int*)(ws + o); o += NNZ_;
    int*   user_slot  = (int*)(ws + o); o += NUSERS;
    int*   iflag      = (int*)(ws + o); o += NITEMS;
    int*   pcnt       = (int*)(ws + o); o += (size_t)NBLK * NBINS;
    int*   tot        = (int*)(ws + o); o += NBINS;
    int*   binbase    = (int*)(ws + o); o += NBINS + 1;
    int*   obase      = (int*)(ws + o); o += (size_t)NBLK * NBINS;
    size_t o_pref = o;
    size_t zz = (size_t)RREL * BB * 64 * 2 + RREL * BB + BB * KK;   // zero zone words
    size_t need_small = o_pref + PM + zz;                            // 1 prop2, itf2 aliased
    size_t need_big   = o_pref + 4 * PM + zz;                        // 3 prop2 + itf2
    bool big = (ws_size >= need_big * 4);
    if (!big && ws_size < need_small * 4) return;   // can't run safely

    float* prop2 = ws + o;          o += big ? 3 * PM : PM;
    float* itf2  = big ? ws + o : prop2;  if (big) o += PM;
    float* acc_neigh = ws + o;      o += (size_t)RREL * BB * 64;
    float* acc_prop  = ws + o;      o += (size_t)RREL * BB * 64;
    float* ubc       = ws + o;      o += (size_t)RREL * BB;
    float* score2    = ws + o;      o += (size_t)BB * KK;

    // phase 0: init
    hipMemsetAsync(user_slot, 0xFF, (size_t)NUSERS * 4, stream);
    hipMemsetAsync(iflag, 0, (size_t)NITEMS * 4, stream);
    hipMemsetAsync(acc_neigh, 0, zz * 4, stream);
    hipMemsetAsync(out + (out_size - 1), 0, 4, stream);
    scatter_maps<<<(BB * KK + 255) / 256, 256, 0, stream>>>(user, item, user_slot, iflag);

    // phase 1: atomic-free coarse bucketing
    pass1_count<<<NBLK, BTH, 0, stream>>>(ig_rows, train_cols, pcnt);
    scan_tot<<<(NBINS + 255) / 256, 256, 0, stream>>>(pcnt, tot);
    scan_bins<<<1, 1024, 0, stream>>>(tot, binbase);
    scan_obase<<<(NBINS + 255) / 256, 256, 0, stream>>>(pcnt, binbase, obase);
    pass2_scatter<<<NBLK, BTH, 0, stream>>>(ig_rows, ig_cols, ig_vals, train_rows, train_cols,
                                            obase, garr, tcol);

    if (big) {
        // fused: one launch per phase across all segments/relations
        gather_all<<<4 * NBIN_SEG, GTH, 0, stream>>>(item_emb, user_emb, binbase, garr, tcol,
                                                     iflag, prop2, PM, itf2, 0);
        apply_all<<<4 * BPM, 256, 0, stream>>>(prop2, PM, itf2, Wp, W, iflag, 0);
        rel_scan_all<<<2048, 256, 0, stream>>>(rel_rows, rel_cols, user_slot, item_emb,
                                               prop2, PM, acc_neigh, acc_prop, ubc, 0, RREL);
        proj_all<<<RREL * BB, 256, 0, stream>>>(user, user_slot, ubc, acc_neigh, acc_prop, Wb,
                                                item, item_emb, prop2, PM, score2, 0);
    } else {
        // legacy: per-relation sequential, single prop2 buffer (itf2 aliased)
        for (int i = 0; i < RREL; i++) {
            gather_all<<<NBIN_SEG, GTH, 0, stream>>>(item_emb, user_emb, binbase, garr, tcol,
                                                     iflag, prop2, 0, itf2, i);
            apply_all<<<BPM, 256, 0, stream>>>(prop2, 0, itf2, Wp, W, iflag, i);
            rel_scan_all<<<1024, 256, 0, stream>>>(rel_rows, rel_cols, user_slot, item_emb,
                                                   prop2, 0, acc_neigh, acc_prop, ubc, i, 1);
            proj_all<<<BB, 256, 0, stream>>>(user, user_slot, ubc, acc_neigh, acc_prop, Wb,
                                             item, item_emb, prop2, 0, score2, i);
        }
        gather_all<<<NBIN_SEG, GTH, 0, stream>>>(item_emb, user_emb, binbase, garr, tcol,
                                                 iflag, prop2, 0, itf2, 3);
        apply_all<<<BPM, 256, 0, stream>>>(prop2, 0, itf2, Wp, W, iflag, 3);
    }

    final_k<<<BB, 256, 0, stream>>>(user, item, user_slot, ubc, acc_neigh, mw, W,
                                    user_emb, item_emb, itf2, score2,
                                    out, out + (out_size - 1));
}